// Round 1
// baseline (4361.259 us; speedup 1.0000x reference)
//
#include <hip/hip_runtime.h>

#define EPS_BN 1e-5f

constexpr int NN   = 20000;       // nodes
constexpr int NE   = 320000;      // edges
constexpr int NTOT = NE + NN;     // edges + self loops
constexpr int NG   = 512;         // graphs

// ------------------------------------------------------------------
// Graph preprocessing
// ------------------------------------------------------------------
__global__ void k_deg(const int* __restrict__ col, int* __restrict__ deg) {
  int e = blockIdx.x * blockDim.x + threadIdx.x;
  if (e >= NTOT) return;
  int c = (e < NE) ? col[e] : (e - NE);
  atomicAdd(&deg[c], 1);
}

__global__ void k_dinv(const int* __restrict__ deg, float* __restrict__ dinv) {
  int i = blockIdx.x * blockDim.x + threadIdx.x;
  if (i < NN) dinv[i] = rsqrtf((float)deg[i]);   // deg >= 1 (self loop)
}

// single-block exclusive scan (n <= 20480); also copies result into cursor
__global__ __launch_bounds__(1024) void k_scan(const int* __restrict__ counts, int n,
                                               int* __restrict__ out_ptr,
                                               int* __restrict__ cursor) {
  __shared__ int ssum[1024];
  int tid = threadIdx.x;
  int per = (n + 1023) / 1024;
  int beg = tid * per;
  int end = min(beg + per, n);
  int s = 0;
  for (int i = beg; i < end; ++i) s += counts[i];
  ssum[tid] = s;
  __syncthreads();
  for (int off = 1; off < 1024; off <<= 1) {
    int v = ssum[tid];
    int add = (tid >= off) ? ssum[tid - off] : 0;
    __syncthreads();
    ssum[tid] = v + add;
    __syncthreads();
  }
  int excl = (tid == 0) ? 0 : ssum[tid - 1];
  for (int i = beg; i < end; ++i) {
    out_ptr[i] = excl;
    cursor[i]  = excl;
    excl += counts[i];
  }
  if (tid == 1023) out_ptr[n] = ssum[1023];
}

__global__ void k_fill(const int* __restrict__ row, const int* __restrict__ col,
                       const float* __restrict__ dinv, int* __restrict__ cursor,
                       int* __restrict__ csr_src, float* __restrict__ csr_w) {
  int e = blockIdx.x * blockDim.x + threadIdx.x;
  if (e >= NTOT) return;
  int r, c;
  if (e < NE) { r = row[e]; c = col[e]; } else { r = c = e - NE; }
  int pos = atomicAdd(&cursor[c], 1);
  csr_src[pos] = r;
  csr_w[pos]   = dinv[r] * dinv[c];
}

__global__ void k_gcnt(const int* __restrict__ batch, int* __restrict__ cnt) {
  int n = blockIdx.x * blockDim.x + threadIdx.x;
  if (n < NN) atomicAdd(&cnt[batch[n]], 1);
}

// ------------------------------------------------------------------
// Gather aggregation: Y[c,:] = sum_e w_e * X[src_e,:]  (+bias, relu)
// one block per destination node
// ------------------------------------------------------------------
#define AGG_T  128
#define AGG_CH 128
__global__ __launch_bounds__(AGG_T) void k_agg(
    const float* __restrict__ X, float* __restrict__ Y,
    const int* __restrict__ indptr, const int* __restrict__ src,
    const float* __restrict__ w, int F,
    const float* __restrict__ bias, int do_relu) {
  __shared__ int   s_src[AGG_CH];
  __shared__ float s_w[AGG_CH];
  int node = blockIdx.x;
  int tid  = threadIdx.x;
  int beg = indptr[node], end = indptr[node + 1];
  float acc[4] = {0.f, 0.f, 0.f, 0.f};
  int nf = (F + AGG_T - 1) / AGG_T;   // <= 4 (F <= 512)
  for (int e0 = beg; e0 < end; e0 += AGG_CH) {
    int c = min(AGG_CH, end - e0);
    if (tid < c) { s_src[tid] = src[e0 + tid]; s_w[tid] = w[e0 + tid]; }
    __syncthreads();
    for (int j = 0; j < c; ++j) {
      const float* xr = X + (size_t)s_src[j] * F;
      float we = s_w[j];
      #pragma unroll
      for (int i = 0; i < 4; ++i) {
        int f = tid + i * AGG_T;
        if (i < nf && f < F) acc[i] += we * xr[f];
      }
    }
    __syncthreads();
  }
  #pragma unroll
  for (int i = 0; i < 4; ++i) {
    int f = tid + i * AGG_T;
    if (i < nf && f < F) {
      float v = acc[i];
      if (bias) v += bias[f];
      if (do_relu) v = fmaxf(v, 0.f);
      Y[(size_t)node * F + f] = v;
    }
  }
}

// ------------------------------------------------------------------
// fp32 GEMM: C[M,N] = A[M,K] @ B[K,N] (+bias, relu). 128x128 tile, 8x8/thread.
// ------------------------------------------------------------------
__global__ __launch_bounds__(256) void k_gemm(
    const float* __restrict__ A, const float* __restrict__ B,
    const float* __restrict__ bias, float* __restrict__ C,
    int M, int N, int K, int do_relu) {
  __shared__ float As[16][132];
  __shared__ float Bs[16][132];
  const int tid = threadIdx.x;
  const int tx = tid & 15;   // col group
  const int ty = tid >> 4;   // row group
  const int row0 = blockIdx.y * 128;
  const int col0 = blockIdx.x * 128;
  float acc[8][8] = {};

  for (int k0 = 0; k0 < K; k0 += 16) {
    #pragma unroll
    for (int i = 0; i < 8; ++i) {          // A tile 128x16
      int l = tid + i * 256;
      int k = l & 15, m = l >> 4;
      int gr = row0 + m, gk = k0 + k;
      float v = 0.f;
      if (gr < M && gk < K) v = A[(size_t)gr * K + gk];
      As[k][m] = v;
    }
    #pragma unroll
    for (int i = 0; i < 8; ++i) {          // B tile 16x128
      int l = tid + i * 256;
      int n = l & 127, k = l >> 7;
      int gk = k0 + k, gc = col0 + n;
      float v = 0.f;
      if (gk < K && gc < N) v = B[(size_t)gk * N + gc];
      Bs[k][n] = v;
    }
    __syncthreads();
    #pragma unroll
    for (int k = 0; k < 16; ++k) {
      float4 a0 = *(const float4*)(&As[k][ty * 8]);
      float4 a1 = *(const float4*)(&As[k][ty * 8 + 4]);
      float4 b0 = *(const float4*)(&Bs[k][tx * 8]);
      float4 b1 = *(const float4*)(&Bs[k][tx * 8 + 4]);
      float a[8] = {a0.x, a0.y, a0.z, a0.w, a1.x, a1.y, a1.z, a1.w};
      float b[8] = {b0.x, b0.y, b0.z, b0.w, b1.x, b1.y, b1.z, b1.w};
      #pragma unroll
      for (int i = 0; i < 8; ++i)
        #pragma unroll
        for (int j = 0; j < 8; ++j)
          acc[i][j] = fmaf(a[i], b[j], acc[i][j]);
    }
    __syncthreads();
  }

  #pragma unroll
  for (int i = 0; i < 8; ++i) {
    int r = row0 + ty * 8 + i;
    if (r >= M) break;
    #pragma unroll
    for (int j = 0; j < 8; ++j) {
      int c = col0 + tx * 8 + j;
      float v = acc[i][j];
      if (bias) v += bias[c];
      if (do_relu) v = fmaxf(v, 0.f);
      C[(size_t)r * N + c] = v;
    }
  }
}

// ------------------------------------------------------------------
// BatchNorm (training stats over N rows)
// ------------------------------------------------------------------
__global__ __launch_bounds__(256) void k_bn_stats(const float* __restrict__ X, int F,
                                                  float* __restrict__ sums) {
  int tid = threadIdx.x;
  int nf = F >> 8;                    // F in {256,512,1024}
  float s[4]  = {0, 0, 0, 0};
  float s2[4] = {0, 0, 0, 0};
  int r0 = blockIdx.x * 256;
  int r1 = min(r0 + 256, NN);
  for (int r = r0; r < r1; ++r) {
    const float* xr = X + (size_t)r * F;
    #pragma unroll
    for (int i = 0; i < 4; ++i) {
      if (i < nf) { float v = xr[tid + i * 256]; s[i] += v; s2[i] += v * v; }
    }
  }
  #pragma unroll
  for (int i = 0; i < 4; ++i) {
    if (i < nf) {
      atomicAdd(&sums[tid + i * 256], s[i]);
      atomicAdd(&sums[F + tid + i * 256], s2[i]);
    }
  }
}

__global__ void k_bn_apply(float* __restrict__ X, int F,
                           const float* __restrict__ sums,
                           const float* __restrict__ gamma,
                           const float* __restrict__ beta) {
  size_t idx = (size_t)blockIdx.x * blockDim.x + threadIdx.x;
  if (idx >= (size_t)NN * F) return;
  int f = (int)(idx % F);
  const float inv_n = 1.f / NN;
  float mean = sums[f] * inv_n;
  float var  = sums[F + f] * inv_n - mean * mean;
  float sc   = gamma[f] * rsqrtf(var + EPS_BN);
  X[idx] = (X[idx] - mean) * sc + beta[f];
}

// ------------------------------------------------------------------
// Attention pooling
// ------------------------------------------------------------------
__global__ __launch_bounds__(256) void k_gate(const float* __restrict__ X,
                                              const float* __restrict__ Wg,
                                              const float* __restrict__ bg,
                                              float* __restrict__ gate) {
  __shared__ float red[256];
  int n = blockIdx.x, tid = threadIdx.x;
  const float* xr = X + (size_t)n * 1024;
  float s = 0.f;
  #pragma unroll
  for (int i = 0; i < 4; ++i) { int f = tid + i * 256; s += xr[f] * Wg[f]; }
  red[tid] = s;
  __syncthreads();
  for (int o = 128; o > 0; o >>= 1) {
    if (tid < o) red[tid] += red[tid + o];
    __syncthreads();
  }
  if (tid == 0) gate[n] = red[0] + bg[0];
}

__global__ __launch_bounds__(64) void k_segred(const float* __restrict__ gate,
                                               const int* __restrict__ goff,
                                               float* __restrict__ gmax,
                                               float* __restrict__ gsum) {
  int g = blockIdx.x, tid = threadIdx.x;
  int beg = goff[g], end = goff[g + 1];
  float m = -3.4e38f;
  for (int n = beg + tid; n < end; n += 64) m = fmaxf(m, gate[n]);
  for (int o = 32; o > 0; o >>= 1) m = fmaxf(m, __shfl_down(m, o, 64));
  m = __shfl(m, 0, 64);
  float s = 0.f;
  for (int n = beg + tid; n < end; n += 64) s += expf(gate[n] - m);
  for (int o = 32; o > 0; o >>= 1) s += __shfl_down(s, o, 64);
  if (tid == 0) { gmax[g] = m; gsum[g] = s; }
}

__global__ __launch_bounds__(256) void k_pool(const float* __restrict__ X,
                                              const float* __restrict__ gate,
                                              const int* __restrict__ goff,
                                              const float* __restrict__ gmax,
                                              const float* __restrict__ gsum,
                                              float* __restrict__ pooled) {
  int g = blockIdx.x, tid = threadIdx.x;
  int beg = goff[g], end = goff[g + 1];
  float acc[4] = {0.f, 0.f, 0.f, 0.f};
  if (end > beg) {
    float m = gmax[g], inv = 1.f / gsum[g];
    for (int n = beg; n < end; ++n) {
      float a = expf(gate[n] - m) * inv;
      const float* xr = X + (size_t)n * 1024;
      #pragma unroll
      for (int i = 0; i < 4; ++i) acc[i] += a * xr[tid + i * 256];
    }
  }
  #pragma unroll
  for (int i = 0; i < 4; ++i) pooled[(size_t)g * 1024 + tid + i * 256] = acc[i];
}

// ------------------------------------------------------------------
// MLP head: [1024]->128 relu ->16 relu ->1, one block per graph
// ------------------------------------------------------------------
__global__ __launch_bounds__(128) void k_head(const float* __restrict__ pooled,
                                              const float* __restrict__ Wf2, const float* __restrict__ bf2,
                                              const float* __restrict__ Wf3, const float* __restrict__ bf3,
                                              const float* __restrict__ Wf4, const float* __restrict__ bf4,
                                              float* __restrict__ out) {
  __shared__ float sp[1024];
  __shared__ float sp2[128];
  __shared__ float sp3[16];
  int g = blockIdx.x, tid = threadIdx.x;
  #pragma unroll
  for (int i = 0; i < 8; ++i) sp[tid + i * 128] = pooled[(size_t)g * 1024 + tid + i * 128];
  __syncthreads();
  float s = bf2[tid];
  for (int k = 0; k < 1024; ++k) s += sp[k] * Wf2[k * 128 + tid];
  sp2[tid] = fmaxf(s, 0.f);
  __syncthreads();
  if (tid < 16) {
    float t = bf3[tid];
    for (int k = 0; k < 128; ++k) t += sp2[k] * Wf3[k * 16 + tid];
    sp3[tid] = fmaxf(t, 0.f);
  }
  __syncthreads();
  if (tid == 0) {
    float t = bf4[0];
    for (int k = 0; k < 16; ++k) t += sp3[k] * Wf4[k];
    out[g] = t;
  }
}

// ------------------------------------------------------------------
extern "C" void kernel_launch(void* const* d_in, const int* in_sizes, int n_in,
                              void* d_out, int out_size, void* d_ws, size_t ws_size,
                              hipStream_t stream) {
  const float* x     = (const float*)d_in[0];
  const int*   ei    = (const int*)d_in[1];
  const int*   batch = (const int*)d_in[2];
  const float* W[5]; const float* b[5]; const float* g[5]; const float* be[5];
  for (int l = 0; l < 5; ++l) {
    W[l]  = (const float*)d_in[3 + 4 * l];
    b[l]  = (const float*)d_in[4 + 4 * l];
    g[l]  = (const float*)d_in[5 + 4 * l];
    be[l] = (const float*)d_in[6 + 4 * l];
  }
  const float* Wg  = (const float*)d_in[23];
  const float* bg  = (const float*)d_in[24];
  const float* Wf2 = (const float*)d_in[25];
  const float* bf2 = (const float*)d_in[26];
  const float* Wf3 = (const float*)d_in[27];
  const float* bf3 = (const float*)d_in[28];
  const float* Wf4 = (const float*)d_in[29];
  const float* bf4 = (const float*)d_in[30];
  float* out = (float*)d_out;

  const int* row = ei;        // edge_index[0]
  const int* col = ei + NE;   // edge_index[1]

  // workspace layout
  char* base = (char*)d_ws;
  size_t off = 0;
  auto alloc = [&](size_t bytes) -> char* {
    char* p = base + off;
    off = (off + bytes + 255) & ~(size_t)255;
    return p;
  };
  float* B0      = (float*)alloc((size_t)NN * 1024 * 4);
  float* B1      = (float*)alloc((size_t)NN * 512 * 4);
  float* dinv    = (float*)alloc(NN * 4);
  int*   deg     = (int*)alloc(NN * 4);
  int*   indptr  = (int*)alloc((NN + 1) * 4);
  int*   cursor  = (int*)alloc(NN * 4);
  int*   csr_src = (int*)alloc((size_t)NTOT * 4);
  float* csr_w   = (float*)alloc((size_t)NTOT * 4);
  int*   gcnt    = (int*)alloc(NG * 4);
  int*   goff    = (int*)alloc((NG + 1) * 4);
  int*   gcur    = (int*)alloc(NG * 4);
  float* gate    = (float*)alloc(NN * 4);
  float* gmax    = (float*)alloc(NG * 4);
  float* gsum    = (float*)alloc(NG * 4);
  float* pooled  = (float*)alloc((size_t)NG * 1024 * 4);
  float* bnsum   = (float*)alloc(2 * 1024 * 4);

  // ---- preprocessing ----
  hipMemsetAsync(deg, 0, NN * 4, stream);
  hipMemsetAsync(gcnt, 0, NG * 4, stream);
  k_deg<<<(NTOT + 255) / 256, 256, 0, stream>>>(col, deg);
  k_dinv<<<(NN + 255) / 256, 256, 0, stream>>>(deg, dinv);
  k_scan<<<1, 1024, 0, stream>>>(deg, NN, indptr, cursor);
  k_fill<<<(NTOT + 255) / 256, 256, 0, stream>>>(row, col, dinv, cursor, csr_src, csr_w);
  k_gcnt<<<(NN + 255) / 256, 256, 0, stream>>>(batch, gcnt);
  k_scan<<<1, 1024, 0, stream>>>(gcnt, NG, goff, gcur);

  auto gemm = [&](const float* A, const float* Bm, const float* bias, float* C,
                  int M, int N, int K, int relu) {
    dim3 grid(N / 128, (M + 127) / 128);
    k_gemm<<<grid, 256, 0, stream>>>(A, Bm, bias, C, M, N, K, relu);
  };
  auto agg = [&](const float* X, float* Y, int F, const float* bias, int relu) {
    k_agg<<<NN, AGG_T, 0, stream>>>(X, Y, indptr, csr_src, csr_w, F, bias, relu);
  };
  auto bn = [&](float* H, int F, const float* gm, const float* bt) {
    hipMemsetAsync(bnsum, 0, 2 * F * sizeof(float), stream);
    k_bn_stats<<<(NN + 255) / 256, 256, 0, stream>>>(H, F, bnsum);
    size_t tot = (size_t)NN * F;
    k_bn_apply<<<(int)((tot + 255) / 256), 256, 0, stream>>>(H, F, bnsum, gm, bt);
  };

  // ---- layer 1 (29 -> 1024): aggregate first (29 feats) ----
  agg(x, B1, 29, nullptr, 0);
  gemm(B1, W[0], b[0], B0, NN, 1024, 29, 1);
  bn(B0, 1024, g[0], be[0]);

  // ---- layer 2 (1024 -> 512): transform first, aggregate on 512 ----
  gemm(B0, W[1], nullptr, B1, NN, 512, 1024, 0);
  agg(B1, B0, 512, b[1], 1);
  bn(B0, 512, g[1], be[1]);

  // ---- layer 3 (512 -> 256): transform first, aggregate on 256 ----
  gemm(B0, W[2], nullptr, B1, NN, 256, 512, 0);
  agg(B1, B0, 256, b[2], 1);
  bn(B0, 256, g[2], be[2]);

  // ---- layer 4 (256 -> 512): aggregate first (256 feats) ----
  agg(B0, B1, 256, nullptr, 0);
  gemm(B1, W[3], b[3], B0, NN, 512, 256, 1);
  bn(B0, 512, g[3], be[3]);

  // ---- layer 5 (512 -> 1024): aggregate first (512 feats) ----
  agg(B0, B1, 512, nullptr, 0);
  gemm(B1, W[4], b[4], B0, NN, 1024, 512, 1);
  bn(B0, 1024, g[4], be[4]);

  // ---- attention pooling ----
  k_gate<<<NN, 256, 0, stream>>>(B0, Wg, bg, gate);
  k_segred<<<NG, 64, 0, stream>>>(gate, goff, gmax, gsum);
  k_pool<<<NG, 256, 0, stream>>>(B0, gate, goff, gmax, gsum, pooled);

  // ---- MLP head ----
  k_head<<<NG, 128, 0, stream>>>(pooled, Wf2, bf2, Wf3, bf3, Wf4, bf4, out);
}

// Round 2
// 1413.155 us; speedup vs baseline: 3.0862x; 3.0862x over previous
//
#include <hip/hip_runtime.h>

#define EPS_BN 1e-5f

constexpr int NN   = 20000;       // nodes
constexpr int NE   = 320000;      // edges
constexpr int NTOT = NE + NN;     // edges + self loops
constexpr int NG   = 512;         // graphs
constexpr int MPAD = 20096;       // 157 * 128

typedef short short8 __attribute__((ext_vector_type(8)));
typedef float floatx4 __attribute__((ext_vector_type(4)));

// ------------------------------------------------------------------
// bf16 split helpers
// ------------------------------------------------------------------
__device__ __forceinline__ unsigned short f2bf(float f) {
  unsigned u = __builtin_bit_cast(unsigned, f);
  u += 0x7FFFu + ((u >> 16) & 1u);            // round-to-nearest-even
  return (unsigned short)(u >> 16);
}
__device__ __forceinline__ float bf2f(unsigned short h) {
  unsigned u = ((unsigned)h) << 16;
  return __builtin_bit_cast(float, u);
}
__device__ __forceinline__ void split_bf(float x, unsigned short& hi, unsigned short& lo) {
  hi = f2bf(x);
  lo = f2bf(x - bf2f(hi));
}

__device__ __forceinline__ void gload_lds16(const void* g, void* l) {
  __builtin_amdgcn_global_load_lds(
      (const __attribute__((address_space(1))) void*)g,
      (__attribute__((address_space(3))) void*)l, 16, 0, 0);
}

// ------------------------------------------------------------------
// Graph preprocessing
// ------------------------------------------------------------------
__global__ void k_deg(const int* __restrict__ col, int* __restrict__ deg) {
  int e = blockIdx.x * blockDim.x + threadIdx.x;
  if (e >= NTOT) return;
  int c = (e < NE) ? col[e] : (e - NE);
  atomicAdd(&deg[c], 1);
}

__global__ void k_dinv(const int* __restrict__ deg, float* __restrict__ dinv) {
  int i = blockIdx.x * blockDim.x + threadIdx.x;
  if (i < NN) dinv[i] = rsqrtf((float)deg[i]);
}

__global__ __launch_bounds__(1024) void k_scan(const int* __restrict__ counts, int n,
                                               int* __restrict__ out_ptr,
                                               int* __restrict__ cursor) {
  __shared__ int ssum[1024];
  int tid = threadIdx.x;
  int per = (n + 1023) / 1024;
  int beg = tid * per;
  int end = min(beg + per, n);
  int s = 0;
  for (int i = beg; i < end; ++i) s += counts[i];
  ssum[tid] = s;
  __syncthreads();
  for (int off = 1; off < 1024; off <<= 1) {
    int v = ssum[tid];
    int add = (tid >= off) ? ssum[tid - off] : 0;
    __syncthreads();
    ssum[tid] = v + add;
    __syncthreads();
  }
  int excl = (tid == 0) ? 0 : ssum[tid - 1];
  for (int i = beg; i < end; ++i) {
    out_ptr[i] = excl;
    cursor[i]  = excl;
    excl += counts[i];
  }
  if (tid == 1023) out_ptr[n] = ssum[1023];
}

__global__ void k_fill(const int* __restrict__ row, const int* __restrict__ col,
                       const float* __restrict__ dinv, int* __restrict__ cursor,
                       int* __restrict__ csr_src, float* __restrict__ csr_w) {
  int e = blockIdx.x * blockDim.x + threadIdx.x;
  if (e >= NTOT) return;
  int r, c;
  if (e < NE) { r = row[e]; c = col[e]; } else { r = c = e - NE; }
  int pos = atomicAdd(&cursor[c], 1);
  csr_src[pos] = r;
  csr_w[pos]   = dinv[r] * dinv[c];
}

__global__ void k_gcnt(const int* __restrict__ batch, int* __restrict__ cnt) {
  int n = blockIdx.x * blockDim.x + threadIdx.x;
  if (n < NN) atomicAdd(&cnt[batch[n]], 1);
}

// ------------------------------------------------------------------
// Weight conversion: W [K,N] fp32 -> WT hi/lo bf16 [N,Kpad] (zero pad k>=K)
// ------------------------------------------------------------------
__global__ void k_wconv(const float* __restrict__ W, int K, int N, int Kpad,
                        unsigned short* __restrict__ Thi, unsigned short* __restrict__ Tlo) {
  int idx = blockIdx.x * blockDim.x + threadIdx.x;
  if (idx >= N * Kpad) return;
  int n = idx / Kpad, k = idx - n * Kpad;
  float v = (k < K) ? W[(size_t)k * N + n] : 0.f;
  unsigned short hi, lo;
  split_bf(v, hi, lo);
  Thi[idx] = hi;
  Tlo[idx] = lo;
}

// ------------------------------------------------------------------
// Gather aggregation, fp32 out (+bias, relu): Y[c,:] = sum_e w_e * X[src_e,:]
// ------------------------------------------------------------------
#define AGG_T  128
#define AGG_CH 128
__global__ __launch_bounds__(AGG_T) void k_agg(
    const float* __restrict__ X, float* __restrict__ Y,
    const int* __restrict__ indptr, const int* __restrict__ src,
    const float* __restrict__ w, int F,
    const float* __restrict__ bias, int do_relu) {
  __shared__ int   s_src[AGG_CH];
  __shared__ float s_w[AGG_CH];
  int node = blockIdx.x;
  int tid  = threadIdx.x;
  int beg = indptr[node], end = indptr[node + 1];
  float acc[4] = {0.f, 0.f, 0.f, 0.f};
  int nf = (F + AGG_T - 1) / AGG_T;
  for (int e0 = beg; e0 < end; e0 += AGG_CH) {
    int c = min(AGG_CH, end - e0);
    if (tid < c) { s_src[tid] = src[e0 + tid]; s_w[tid] = w[e0 + tid]; }
    __syncthreads();
    for (int j = 0; j < c; ++j) {
      const float* xr = X + (size_t)s_src[j] * F;
      float we = s_w[j];
      #pragma unroll
      for (int i = 0; i < 4; ++i) {
        int f = tid + i * AGG_T;
        if (i < nf && f < F) acc[i] += we * xr[f];
      }
    }
    __syncthreads();
  }
  #pragma unroll
  for (int i = 0; i < 4; ++i) {
    int f = tid + i * AGG_T;
    if (i < nf && f < F) {
      float v = acc[i];
      if (bias) v += bias[f];
      if (do_relu) v = fmaxf(v, 0.f);
      Y[(size_t)node * F + f] = v;
    }
  }
}

// Gather aggregation, bf16 hi/lo out, row stride Fs (zero pad f>=F)
__global__ __launch_bounds__(AGG_T) void k_agg_split(
    const float* __restrict__ X, int F, int Fs,
    const int* __restrict__ indptr, const int* __restrict__ src,
    const float* __restrict__ w,
    unsigned short* __restrict__ Yhi, unsigned short* __restrict__ Ylo) {
  __shared__ int   s_src[AGG_CH];
  __shared__ float s_w[AGG_CH];
  int node = blockIdx.x;
  int tid  = threadIdx.x;
  int beg = indptr[node], end = indptr[node + 1];
  float acc[4] = {0.f, 0.f, 0.f, 0.f};
  int nf = (F + AGG_T - 1) / AGG_T;
  for (int e0 = beg; e0 < end; e0 += AGG_CH) {
    int c = min(AGG_CH, end - e0);
    if (tid < c) { s_src[tid] = src[e0 + tid]; s_w[tid] = w[e0 + tid]; }
    __syncthreads();
    for (int j = 0; j < c; ++j) {
      const float* xr = X + (size_t)s_src[j] * F;
      float we = s_w[j];
      #pragma unroll
      for (int i = 0; i < 4; ++i) {
        int f = tid + i * AGG_T;
        if (i < nf && f < F) acc[i] += we * xr[f];
      }
    }
    __syncthreads();
  }
  #pragma unroll
  for (int i = 0; i < 4; ++i) {
    int f = tid + i * AGG_T;
    if (f < Fs) {
      unsigned short hi = 0, lo = 0;
      if (f < F) split_bf(acc[i], hi, lo);
      Yhi[(size_t)node * Fs + f] = hi;
      Ylo[(size_t)node * Fs + f] = lo;
    }
  }
}

// ------------------------------------------------------------------
// Split-bf16 MFMA GEMM: C[M,N] = (Ahi+Alo)(Bhi+Blo) (3 terms), +bias, relu.
// A: [M,K] bf16 row-major (hi/lo). B: B^T [N,K] bf16 row-major (hi/lo).
// 128x128 tile, 256 threads = 4 waves (2x2), each wave 64x64 = 4x4 MFMA tiles.
// ------------------------------------------------------------------
__global__ __launch_bounds__(256) void k_gemm_mfma(
    const unsigned short* __restrict__ Ah, const unsigned short* __restrict__ Al,
    const unsigned short* __restrict__ Bh, const unsigned short* __restrict__ Bl,
    const float* __restrict__ bias, float* __restrict__ C,
    int M, int N, int K, int do_relu)
{
  __shared__ __align__(16) unsigned short sAh[128 * 32];
  __shared__ __align__(16) unsigned short sAl[128 * 32];
  __shared__ __align__(16) unsigned short sBh[128 * 32];
  __shared__ __align__(16) unsigned short sBl[128 * 32];

  const int tid  = threadIdx.x;
  const int wave = tid >> 6;
  const int lane = tid & 63;
  const int row0 = blockIdx.y * 128;
  const int col0 = blockIdx.x * 128;

  const int q  = lane >> 4;        // 0..3
  const int mm = lane & 15;
  const int wm = wave >> 1;        // wave row (0..1)
  const int wn = wave & 1;         // wave col (0..1)

  const int srow = lane >> 2;      // 0..15 within a 16-row staging rep
  const int skel = (lane & 3) * 8; // k element offset for this lane

  floatx4 acc[4][4];
  #pragma unroll
  for (int i = 0; i < 4; ++i)
    #pragma unroll
    for (int j = 0; j < 4; ++j) acc[i][j] = floatx4{0.f, 0.f, 0.f, 0.f};

  for (int k0 = 0; k0 < K; k0 += 32) {
    #pragma unroll
    for (int r = 0; r < 2; ++r) {
      int trow = wave * 32 + r * 16;              // tile row of this instr group
      int arow = row0 + trow + srow;
      int brow = col0 + trow + srow;
      gload_lds16(Ah + (size_t)arow * K + k0 + skel, &sAh[trow * 32]);
      gload_lds16(Al + (size_t)arow * K + k0 + skel, &sAl[trow * 32]);
      gload_lds16(Bh + (size_t)brow * K + k0 + skel, &sBh[trow * 32]);
      gload_lds16(Bl + (size_t)brow * K + k0 + skel, &sBl[trow * 32]);
    }
    __syncthreads();

    short8 ah[4], al[4];
    #pragma unroll
    for (int i = 0; i < 4; ++i) {
      int mrow = wm * 64 + i * 16 + mm;
      ah[i] = *(const short8*)&sAh[mrow * 32 + q * 8];
      al[i] = *(const short8*)&sAl[mrow * 32 + q * 8];
    }
    #pragma unroll
    for (int j = 0; j < 4; ++j) {
      int nrow = wn * 64 + j * 16 + mm;
      short8 bh = *(const short8*)&sBh[nrow * 32 + q * 8];
      short8 bl = *(const short8*)&sBl[nrow * 32 + q * 8];
      #pragma unroll
      for (int i = 0; i < 4; ++i) {
        acc[i][j] = __builtin_amdgcn_mfma_f32_16x16x32_bf16(ah[i], bh, acc[i][j], 0, 0, 0);
        acc[i][j] = __builtin_amdgcn_mfma_f32_16x16x32_bf16(ah[i], bl, acc[i][j], 0, 0, 0);
        acc[i][j] = __builtin_amdgcn_mfma_f32_16x16x32_bf16(al[i], bh, acc[i][j], 0, 0, 0);
      }
    }
    __syncthreads();
  }

  #pragma unroll
  for (int j = 0; j < 4; ++j) {
    int cc = col0 + wn * 64 + j * 16 + mm;
    float bv = bias ? bias[cc] : 0.f;
    #pragma unroll
    for (int i = 0; i < 4; ++i) {
      #pragma unroll
      for (int r = 0; r < 4; ++r) {
        int rr = row0 + wm * 64 + i * 16 + q * 4 + r;
        if (rr < M) {
          float v = acc[i][j][r] + bv;
          if (do_relu) v = fmaxf(v, 0.f);
          C[(size_t)rr * N + cc] = v;
        }
      }
    }
  }
}

// ------------------------------------------------------------------
// BatchNorm
// ------------------------------------------------------------------
__global__ __launch_bounds__(256) void k_bn_stats(const float* __restrict__ X, int F,
                                                  float* __restrict__ sums) {
  int tid = threadIdx.x;
  int nf = F >> 8;
  float s[4]  = {0, 0, 0, 0};
  float s2[4] = {0, 0, 0, 0};
  for (int r = blockIdx.x; r < NN; r += gridDim.x) {
    const float* xr = X + (size_t)r * F;
    #pragma unroll
    for (int i = 0; i < 4; ++i) {
      if (i < nf) { float v = xr[tid + i * 256]; s[i] += v; s2[i] += v * v; }
    }
  }
  #pragma unroll
  for (int i = 0; i < 4; ++i) {
    if (i < nf) {
      atomicAdd(&sums[tid + i * 256], s[i]);
      atomicAdd(&sums[F + tid + i * 256], s2[i]);
    }
  }
}

__global__ void k_bn_apply(float* __restrict__ X, int F,
                           const float* __restrict__ sums,
                           const float* __restrict__ gamma,
                           const float* __restrict__ beta) {
  size_t idx = (size_t)blockIdx.x * blockDim.x + threadIdx.x;
  if (idx >= (size_t)NN * F) return;
  int f = (int)(idx % F);
  const float inv_n = 1.f / NN;
  float mean = sums[f] * inv_n;
  float var  = sums[F + f] * inv_n - mean * mean;
  float sc   = gamma[f] * rsqrtf(var + EPS_BN);
  X[idx] = (X[idx] - mean) * sc + beta[f];
}

__global__ void k_bn_apply_split(const float* __restrict__ X, int F,
                                 const float* __restrict__ sums,
                                 const float* __restrict__ gamma,
                                 const float* __restrict__ beta,
                                 unsigned short* __restrict__ Yhi,
                                 unsigned short* __restrict__ Ylo) {
  size_t idx = (size_t)blockIdx.x * blockDim.x + threadIdx.x;
  if (idx >= (size_t)NN * F) return;
  int f = (int)(idx % F);
  const float inv_n = 1.f / NN;
  float mean = sums[f] * inv_n;
  float var  = sums[F + f] * inv_n - mean * mean;
  float sc   = gamma[f] * rsqrtf(var + EPS_BN);
  float v = (X[idx] - mean) * sc + beta[f];
  unsigned short hi, lo;
  split_bf(v, hi, lo);
  Yhi[idx] = hi;
  Ylo[idx] = lo;
}

// ------------------------------------------------------------------
// Attention pooling
// ------------------------------------------------------------------
__global__ __launch_bounds__(256) void k_gate(const float* __restrict__ X,
                                              const float* __restrict__ Wg,
                                              const float* __restrict__ bg,
                                              float* __restrict__ gate) {
  __shared__ float red[256];
  int n = blockIdx.x, tid = threadIdx.x;
  const float* xr = X + (size_t)n * 1024;
  float s = 0.f;
  #pragma unroll
  for (int i = 0; i < 4; ++i) { int f = tid + i * 256; s += xr[f] * Wg[f]; }
  red[tid] = s;
  __syncthreads();
  for (int o = 128; o > 0; o >>= 1) {
    if (tid < o) red[tid] += red[tid + o];
    __syncthreads();
  }
  if (tid == 0) gate[n] = red[0] + bg[0];
}

__global__ __launch_bounds__(64) void k_segred(const float* __restrict__ gate,
                                               const int* __restrict__ goff,
                                               float* __restrict__ gmax,
                                               float* __restrict__ gsum) {
  int g = blockIdx.x, tid = threadIdx.x;
  int beg = goff[g], end = goff[g + 1];
  float m = -3.4e38f;
  for (int n = beg + tid; n < end; n += 64) m = fmaxf(m, gate[n]);
  for (int o = 32; o > 0; o >>= 1) m = fmaxf(m, __shfl_down(m, o, 64));
  m = __shfl(m, 0, 64);
  float s = 0.f;
  for (int n = beg + tid; n < end; n += 64) s += expf(gate[n] - m);
  for (int o = 32; o > 0; o >>= 1) s += __shfl_down(s, o, 64);
  if (tid == 0) { gmax[g] = m; gsum[g] = s; }
}

__global__ __launch_bounds__(256) void k_pool(const float* __restrict__ X,
                                              const float* __restrict__ gate,
                                              const int* __restrict__ goff,
                                              const float* __restrict__ gmax,
                                              const float* __restrict__ gsum,
                                              float* __restrict__ pooled) {
  int g = blockIdx.x, tid = threadIdx.x;
  int beg = goff[g], end = goff[g + 1];
  float acc[4] = {0.f, 0.f, 0.f, 0.f};
  if (end > beg) {
    float m = gmax[g], inv = 1.f / gsum[g];
    for (int n = beg; n < end; ++n) {
      float a = expf(gate[n] - m) * inv;
      const float* xr = X + (size_t)n * 1024;
      #pragma unroll
      for (int i = 0; i < 4; ++i) acc[i] += a * xr[tid + i * 256];
    }
  }
  #pragma unroll
  for (int i = 0; i < 4; ++i) pooled[(size_t)g * 1024 + tid + i * 256] = acc[i];
}

// ------------------------------------------------------------------
// MLP head
// ------------------------------------------------------------------
__global__ __launch_bounds__(128) void k_head(const float* __restrict__ pooled,
                                              const float* __restrict__ Wf2, const float* __restrict__ bf2,
                                              const float* __restrict__ Wf3, const float* __restrict__ bf3,
                                              const float* __restrict__ Wf4, const float* __restrict__ bf4,
                                              float* __restrict__ out) {
  __shared__ float sp[1024];
  __shared__ float sp2[128];
  __shared__ float sp3[16];
  int g = blockIdx.x, tid = threadIdx.x;
  #pragma unroll
  for (int i = 0; i < 8; ++i) sp[tid + i * 128] = pooled[(size_t)g * 1024 + tid + i * 128];
  __syncthreads();
  float s = bf2[tid];
  for (int k = 0; k < 1024; ++k) s += sp[k] * Wf2[k * 128 + tid];
  sp2[tid] = fmaxf(s, 0.f);
  __syncthreads();
  if (tid < 16) {
    float t = bf3[tid];
    for (int k = 0; k < 128; ++k) t += sp2[k] * Wf3[k * 16 + tid];
    sp3[tid] = fmaxf(t, 0.f);
  }
  __syncthreads();
  if (tid == 0) {
    float t = bf4[0];
    for (int k = 0; k < 16; ++k) t += sp3[k] * Wf4[k];
    out[g] = t;
  }
}

// ------------------------------------------------------------------
extern "C" void kernel_launch(void* const* d_in, const int* in_sizes, int n_in,
                              void* d_out, int out_size, void* d_ws, size_t ws_size,
                              hipStream_t stream) {
  const float* x     = (const float*)d_in[0];
  const int*   ei    = (const int*)d_in[1];
  const int*   batch = (const int*)d_in[2];
  const float* W[5]; const float* b[5]; const float* g[5]; const float* be[5];
  for (int l = 0; l < 5; ++l) {
    W[l]  = (const float*)d_in[3 + 4 * l];
    b[l]  = (const float*)d_in[4 + 4 * l];
    g[l]  = (const float*)d_in[5 + 4 * l];
    be[l] = (const float*)d_in[6 + 4 * l];
  }
  const float* Wg  = (const float*)d_in[23];
  const float* bg  = (const float*)d_in[24];
  const float* Wf2 = (const float*)d_in[25];
  const float* bf2 = (const float*)d_in[26];
  const float* Wf3 = (const float*)d_in[27];
  const float* bf3 = (const float*)d_in[28];
  const float* Wf4 = (const float*)d_in[29];
  const float* bf4 = (const float*)d_in[30];
  float* out = (float*)d_out;

  const int* row = ei;
  const int* col = ei + NE;

  char* base = (char*)d_ws;
  size_t off = 0;
  auto alloc = [&](size_t bytes) -> char* {
    char* p = base + off;
    off = (off + bytes + 255) & ~(size_t)255;
    return p;
  };
  float* B0   = (float*)alloc((size_t)NN * 1024 * 4);
  float* B1   = (float*)alloc((size_t)NN * 512 * 4);
  unsigned short* Ahi = (unsigned short*)alloc((size_t)MPAD * 1024 * 2);
  unsigned short* Alo = (unsigned short*)alloc((size_t)MPAD * 1024 * 2);
  unsigned short* A32hi = (unsigned short*)alloc((size_t)MPAD * 32 * 2);
  unsigned short* A32lo = (unsigned short*)alloc((size_t)MPAD * 32 * 2);
  // transposed split weights
  const int wtsz[5] = {1024 * 32, 512 * 1024, 256 * 512, 512 * 256, 1024 * 512};
  unsigned short* WTh[5]; unsigned short* WTl[5];
  for (int l = 0; l < 5; ++l) {
    WTh[l] = (unsigned short*)alloc((size_t)wtsz[l] * 2);
    WTl[l] = (unsigned short*)alloc((size_t)wtsz[l] * 2);
  }
  float* dinv    = (float*)alloc(NN * 4);
  int*   deg     = (int*)alloc(NN * 4);
  int*   indptr  = (int*)alloc((NN + 1) * 4);
  int*   cursor  = (int*)alloc(NN * 4);
  int*   csr_src = (int*)alloc((size_t)NTOT * 4);
  float* csr_w   = (float*)alloc((size_t)NTOT * 4);
  int*   gcnt    = (int*)alloc(NG * 4);
  int*   goff    = (int*)alloc((NG + 1) * 4);
  int*   gcur    = (int*)alloc(NG * 4);
  float* gate    = (float*)alloc(NN * 4);
  float* gmax    = (float*)alloc(NG * 4);
  float* gsum    = (float*)alloc(NG * 4);
  float* pooled  = (float*)alloc((size_t)NG * 1024 * 4);
  float* bnsum   = (float*)alloc(2 * 1024 * 4);

  // ---- preprocessing ----
  hipMemsetAsync(deg, 0, NN * 4, stream);
  hipMemsetAsync(gcnt, 0, NG * 4, stream);
  k_deg<<<(NTOT + 255) / 256, 256, 0, stream>>>(col, deg);
  k_dinv<<<(NN + 255) / 256, 256, 0, stream>>>(deg, dinv);
  k_scan<<<1, 1024, 0, stream>>>(deg, NN, indptr, cursor);
  k_fill<<<(NTOT + 255) / 256, 256, 0, stream>>>(row, col, dinv, cursor, csr_src, csr_w);
  k_gcnt<<<(NN + 255) / 256, 256, 0, stream>>>(batch, gcnt);
  k_scan<<<1, 1024, 0, stream>>>(gcnt, NG, goff, gcur);

  // ---- weight split/transpose ----
  const int wK[5] = {29, 1024, 512, 256, 512};
  const int wN[5] = {1024, 512, 256, 512, 1024};
  const int wKp[5] = {32, 1024, 512, 256, 512};
  for (int l = 0; l < 5; ++l) {
    int tot = wN[l] * wKp[l];
    k_wconv<<<(tot + 255) / 256, 256, 0, stream>>>(W[l], wK[l], wN[l], wKp[l], WTh[l], WTl[l]);
  }

  auto gemm = [&](const unsigned short* ah, const unsigned short* al, int l,
                  const float* bias, float* C, int N, int K, int relu) {
    dim3 grid(N / 128, MPAD / 128);
    k_gemm_mfma<<<grid, 256, 0, stream>>>(ah, al, WTh[l], WTl[l], bias, C, NN, N, K, relu);
  };
  auto bnstats = [&](const float* H, int F) {
    hipMemsetAsync(bnsum, 0, 2 * F * sizeof(float), stream);
    k_bn_stats<<<512, 256, 0, stream>>>(H, F, bnsum);
  };

  // ---- layer 1 (29 -> 1024): aggregate first on 29 feats ----
  k_agg_split<<<NN, AGG_T, 0, stream>>>(x, 29, 32, indptr, csr_src, csr_w, A32hi, A32lo);
  gemm(A32hi, A32lo, 0, b[0], B0, 1024, 32, 1);
  bnstats(B0, 1024);
  k_bn_apply_split<<<(int)(((size_t)NN * 1024 + 255) / 256), 256, 0, stream>>>(
      B0, 1024, bnsum, g[0], be[0], Ahi, Alo);

  // ---- layer 2 (1024 -> 512): transform first, aggregate on 512 ----
  gemm(Ahi, Alo, 1, nullptr, B1, 512, 1024, 0);
  k_agg<<<NN, AGG_T, 0, stream>>>(B1, B0, indptr, csr_src, csr_w, 512, b[1], 1);
  bnstats(B0, 512);
  k_bn_apply_split<<<(int)(((size_t)NN * 512 + 255) / 256), 256, 0, stream>>>(
      B0, 512, bnsum, g[1], be[1], Ahi, Alo);

  // ---- layer 3 (512 -> 256): transform first, aggregate on 256 ----
  gemm(Ahi, Alo, 2, nullptr, B1, 256, 512, 0);
  k_agg<<<NN, AGG_T, 0, stream>>>(B1, B0, indptr, csr_src, csr_w, 256, b[2], 1);
  bnstats(B0, 256);
  k_bn_apply<<<(int)(((size_t)NN * 256 + 255) / 256), 256, 0, stream>>>(B0, 256, bnsum, g[2], be[2]);

  // ---- layer 4 (256 -> 512): aggregate first ----
  k_agg_split<<<NN, AGG_T, 0, stream>>>(B0, 256, 256, indptr, csr_src, csr_w, Ahi, Alo);
  gemm(Ahi, Alo, 3, b[3], B1, 512, 256, 1);
  bnstats(B1, 512);
  k_bn_apply<<<(int)(((size_t)NN * 512 + 255) / 256), 256, 0, stream>>>(B1, 512, bnsum, g[3], be[3]);

  // ---- layer 5 (512 -> 1024): aggregate first ----
  k_agg_split<<<NN, AGG_T, 0, stream>>>(B1, 512, 512, indptr, csr_src, csr_w, Ahi, Alo);
  gemm(Ahi, Alo, 4, b[4], B0, 1024, 512, 1);
  bnstats(B0, 1024);
  k_bn_apply<<<(int)(((size_t)NN * 1024 + 255) / 256), 256, 0, stream>>>(B0, 1024, bnsum, g[4], be[4]);

  // ---- attention pooling ----
  k_gate<<<NN, 256, 0, stream>>>(B0, Wg, bg, gate);
  k_segred<<<NG, 64, 0, stream>>>(gate, goff, gmax, gsum);
  k_pool<<<NG, 256, 0, stream>>>(B0, gate, goff, gmax, gsum, pooled);

  // ---- MLP head ----
  k_head<<<NG, 128, 0, stream>>>(pooled, Wf2, bf2, Wf3, bf3, Wf4, bf4, out);
}

// Round 3
// 1095.926 us; speedup vs baseline: 3.9795x; 1.2895x over previous
//
#include <hip/hip_runtime.h>

#define EPS_BN 1e-5f

constexpr int NN   = 20000;       // nodes
constexpr int NE   = 320000;      // edges
constexpr int NTOT = NE + NN;     // edges + self loops
constexpr int NG   = 512;         // graphs
constexpr int MPAD = 20096;       // 157 * 128

typedef short short8 __attribute__((ext_vector_type(8)));
typedef float floatx4 __attribute__((ext_vector_type(4)));

// ------------------------------------------------------------------
// bf16 helpers
// ------------------------------------------------------------------
__device__ __forceinline__ unsigned short f2bf(float f) {
  unsigned u = __builtin_bit_cast(unsigned, f);
  u += 0x7FFFu + ((u >> 16) & 1u);            // round-to-nearest-even
  return (unsigned short)(u >> 16);
}
__device__ __forceinline__ float bf2f(unsigned short h) {
  unsigned u = ((unsigned)h) << 16;
  return __builtin_bit_cast(float, u);
}
__device__ __forceinline__ void split_bf(float x, unsigned short& hi, unsigned short& lo) {
  hi = f2bf(x);
  lo = f2bf(x - bf2f(hi));
}

__device__ __forceinline__ void gload_lds16(const void* g, void* l) {
  __builtin_amdgcn_global_load_lds(
      (const __attribute__((address_space(1))) void*)g,
      (__attribute__((address_space(3))) void*)l, 16, 0, 0);
}

// ------------------------------------------------------------------
// Graph preprocessing
// ------------------------------------------------------------------
__global__ void k_deg(const int* __restrict__ col, int* __restrict__ deg) {
  int e = blockIdx.x * blockDim.x + threadIdx.x;
  if (e >= NTOT) return;
  int c = (e < NE) ? col[e] : (e - NE);
  atomicAdd(&deg[c], 1);
}

__global__ void k_dinv(const int* __restrict__ deg, float* __restrict__ dinv) {
  int i = blockIdx.x * blockDim.x + threadIdx.x;
  if (i < NN) dinv[i] = rsqrtf((float)deg[i]);
}

__global__ __launch_bounds__(1024) void k_scan(const int* __restrict__ counts, int n,
                                               int* __restrict__ out_ptr,
                                               int* __restrict__ cursor) {
  __shared__ int ssum[1024];
  int tid = threadIdx.x;
  int per = (n + 1023) / 1024;
  int beg = tid * per;
  int end = min(beg + per, n);
  int s = 0;
  for (int i = beg; i < end; ++i) s += counts[i];
  ssum[tid] = s;
  __syncthreads();
  for (int off = 1; off < 1024; off <<= 1) {
    int v = ssum[tid];
    int add = (tid >= off) ? ssum[tid - off] : 0;
    __syncthreads();
    ssum[tid] = v + add;
    __syncthreads();
  }
  int excl = (tid == 0) ? 0 : ssum[tid - 1];
  for (int i = beg; i < end; ++i) {
    out_ptr[i] = excl;
    cursor[i]  = excl;
    excl += counts[i];
  }
  if (tid == 1023) out_ptr[n] = ssum[1023];
}

__global__ void k_fill(const int* __restrict__ row, const int* __restrict__ col,
                       const float* __restrict__ dinv, int* __restrict__ cursor,
                       int* __restrict__ csr_src, float* __restrict__ csr_w) {
  int e = blockIdx.x * blockDim.x + threadIdx.x;
  if (e >= NTOT) return;
  int r, c;
  if (e < NE) { r = row[e]; c = col[e]; } else { r = c = e - NE; }
  int pos = atomicAdd(&cursor[c], 1);
  csr_src[pos] = r;
  csr_w[pos]   = dinv[r] * dinv[c];
}

__global__ void k_gcnt(const int* __restrict__ batch, int* __restrict__ cnt) {
  int n = blockIdx.x * blockDim.x + threadIdx.x;
  if (n < NN) atomicAdd(&cnt[batch[n]], 1);
}

// ------------------------------------------------------------------
// Weight conversion: W [K,N] fp32 -> WT hi/lo bf16 [N,Kpad] (zero pad k>=K)
// ------------------------------------------------------------------
__global__ void k_wconv(const float* __restrict__ W, int K, int N, int Kpad,
                        unsigned short* __restrict__ Thi, unsigned short* __restrict__ Tlo) {
  int idx = blockIdx.x * blockDim.x + threadIdx.x;
  if (idx >= N * Kpad) return;
  int n = idx / Kpad, k = idx - n * Kpad;
  float v = (k < K) ? W[(size_t)k * N + n] : 0.f;
  unsigned short hi, lo;
  split_bf(v, hi, lo);
  Thi[idx] = hi;
  Tlo[idx] = lo;
}

// ------------------------------------------------------------------
// L1 aggregation (fp32 in, split bf16 out), F=29, Fs=32
// ------------------------------------------------------------------
#define AGG_T  128
#define AGG_CH 128
__global__ __launch_bounds__(AGG_T) void k_agg_split(
    const float* __restrict__ X, int F, int Fs,
    const int* __restrict__ indptr, const int* __restrict__ src,
    const float* __restrict__ w,
    unsigned short* __restrict__ Yhi, unsigned short* __restrict__ Ylo) {
  __shared__ int   s_src[AGG_CH];
  __shared__ float s_w[AGG_CH];
  int node = blockIdx.x;
  int tid  = threadIdx.x;
  int beg = indptr[node], end = indptr[node + 1];
  float acc = 0.f;
  for (int e0 = beg; e0 < end; e0 += AGG_CH) {
    int c = min(AGG_CH, end - e0);
    if (tid < c) { s_src[tid] = src[e0 + tid]; s_w[tid] = w[e0 + tid]; }
    __syncthreads();
    for (int j = 0; j < c; ++j) {
      if (tid < F) acc += s_w[j] * X[(size_t)s_src[j] * F + tid];
    }
    __syncthreads();
  }
  if (tid < Fs) {
    unsigned short hi = 0, lo = 0;
    if (tid < F) split_bf(acc, hi, lo);
    Yhi[(size_t)node * Fs + tid] = hi;
    Ylo[(size_t)node * Fs + tid] = lo;
  }
}

// ------------------------------------------------------------------
// bf16 gather aggregation, wave-per-node. F = 64*VEC.
// SPLIT=false: Yf = relu(agg + bias) fp32.  SPLIT=true: hi/lo bf16 out.
// ------------------------------------------------------------------
template<int VEC, bool SPLIT>
__global__ __launch_bounds__(256) void k_agg_bf(
    const unsigned short* __restrict__ X,
    const int* __restrict__ indptr, const int* __restrict__ src,
    const float* __restrict__ w,
    const float* __restrict__ bias,
    float* __restrict__ Yf,
    unsigned short* __restrict__ Yhi, unsigned short* __restrict__ Ylo)
{
  constexpr int F = 64 * VEC;
  int wave = threadIdx.x >> 6;
  int lane = threadIdx.x & 63;
  int node = blockIdx.x * 4 + wave;
  int beg = indptr[node], end = indptr[node + 1];
  float acc[VEC];
  #pragma unroll
  for (int i = 0; i < VEC; ++i) acc[i] = 0.f;
  const unsigned int* Xl = (const unsigned int*)(X) + lane * (VEC / 2);

  auto body = [&](int e) {
    int s = src[e];
    float we = w[e];
    const unsigned int* xr = Xl + (size_t)s * (F / 2);
    unsigned int u[VEC / 2];
    if constexpr (VEC == 8) {
      uint4 d = *(const uint4*)xr;
      u[0] = d.x; u[1] = d.y; u[2] = d.z; u[3] = d.w;
    } else {
      uint2 d = *(const uint2*)xr;
      u[0] = d.x; u[1] = d.y;
    }
    #pragma unroll
    for (int i = 0; i < VEC / 2; ++i) {
      float lo = __builtin_bit_cast(float, u[i] << 16);
      float hi = __builtin_bit_cast(float, u[i] & 0xFFFF0000u);
      acc[2 * i]     = fmaf(we, lo, acc[2 * i]);
      acc[2 * i + 1] = fmaf(we, hi, acc[2 * i + 1]);
    }
  };
  int e = beg;
  for (; e + 2 <= end; e += 2) { body(e); body(e + 1); }
  if (e < end) body(e);

  size_t obase = (size_t)node * F + lane * VEC;
  if constexpr (SPLIT) {
    #pragma unroll
    for (int i = 0; i < VEC; ++i) {
      unsigned short hi, lo;
      split_bf(acc[i], hi, lo);
      Yhi[obase + i] = hi;
      Ylo[obase + i] = lo;
    }
  } else {
    #pragma unroll
    for (int i = 0; i < VEC; ++i) {
      float v = fmaxf(acc[i] + bias[lane * VEC + i], 0.f);
      Yf[obase + i] = v;
    }
  }
}

// ------------------------------------------------------------------
// Split-bf16 MFMA GEMM. A: [M,K] hi/lo. B^T: [N,K] hi/lo.
// C fp32 (+bias,relu) if C != null, else bf16 out to Cbf.
// ------------------------------------------------------------------
__global__ __launch_bounds__(256) void k_gemm_mfma(
    const unsigned short* __restrict__ Ah, const unsigned short* __restrict__ Al,
    const unsigned short* __restrict__ Bh, const unsigned short* __restrict__ Bl,
    const float* __restrict__ bias, float* __restrict__ C,
    unsigned short* __restrict__ Cbf,
    int M, int N, int K, int do_relu)
{
  __shared__ __align__(16) unsigned short sAh[128 * 32];
  __shared__ __align__(16) unsigned short sAl[128 * 32];
  __shared__ __align__(16) unsigned short sBh[128 * 32];
  __shared__ __align__(16) unsigned short sBl[128 * 32];

  const int tid  = threadIdx.x;
  const int wave = tid >> 6;
  const int lane = tid & 63;
  const int row0 = blockIdx.y * 128;
  const int col0 = blockIdx.x * 128;

  const int q  = lane >> 4;
  const int mm = lane & 15;
  const int wm = wave >> 1;
  const int wn = wave & 1;

  const int srow = lane >> 2;
  const int skel = (lane & 3) * 8;

  floatx4 acc[4][4];
  #pragma unroll
  for (int i = 0; i < 4; ++i)
    #pragma unroll
    for (int j = 0; j < 4; ++j) acc[i][j] = floatx4{0.f, 0.f, 0.f, 0.f};

  for (int k0 = 0; k0 < K; k0 += 32) {
    #pragma unroll
    for (int r = 0; r < 2; ++r) {
      int trow = wave * 32 + r * 16;
      int arow = row0 + trow + srow;
      int brow = col0 + trow + srow;
      gload_lds16(Ah + (size_t)arow * K + k0 + skel, &sAh[trow * 32]);
      gload_lds16(Al + (size_t)arow * K + k0 + skel, &sAl[trow * 32]);
      gload_lds16(Bh + (size_t)brow * K + k0 + skel, &sBh[trow * 32]);
      gload_lds16(Bl + (size_t)brow * K + k0 + skel, &sBl[trow * 32]);
    }
    __syncthreads();

    short8 ah[4], al[4];
    #pragma unroll
    for (int i = 0; i < 4; ++i) {
      int mrow = wm * 64 + i * 16 + mm;
      ah[i] = *(const short8*)&sAh[mrow * 32 + q * 8];
      al[i] = *(const short8*)&sAl[mrow * 32 + q * 8];
    }
    #pragma unroll
    for (int j = 0; j < 4; ++j) {
      int nrow = wn * 64 + j * 16 + mm;
      short8 bh = *(const short8*)&sBh[nrow * 32 + q * 8];
      short8 bl = *(const short8*)&sBl[nrow * 32 + q * 8];
      #pragma unroll
      for (int i = 0; i < 4; ++i) {
        acc[i][j] = __builtin_amdgcn_mfma_f32_16x16x32_bf16(ah[i], bh, acc[i][j], 0, 0, 0);
        acc[i][j] = __builtin_amdgcn_mfma_f32_16x16x32_bf16(ah[i], bl, acc[i][j], 0, 0, 0);
        acc[i][j] = __builtin_amdgcn_mfma_f32_16x16x32_bf16(al[i], bh, acc[i][j], 0, 0, 0);
      }
    }
    __syncthreads();
  }

  #pragma unroll
  for (int j = 0; j < 4; ++j) {
    int cc = col0 + wn * 64 + j * 16 + mm;
    float bv = bias ? bias[cc] : 0.f;
    #pragma unroll
    for (int i = 0; i < 4; ++i) {
      #pragma unroll
      for (int r = 0; r < 4; ++r) {
        int rr = row0 + wm * 64 + i * 16 + q * 4 + r;
        if (rr < M) {
          float v = acc[i][j][r] + bv;
          if (do_relu) v = fmaxf(v, 0.f);
          if (C) C[(size_t)rr * N + cc] = v;
          else   Cbf[(size_t)rr * N + cc] = f2bf(v);
        }
      }
    }
  }
}

// ------------------------------------------------------------------
// BatchNorm
// ------------------------------------------------------------------
__global__ __launch_bounds__(256) void k_bn_stats(const float* __restrict__ X, int F,
                                                  float* __restrict__ sums) {
  int tid = threadIdx.x;
  int nf = F >> 8;
  float s[4]  = {0, 0, 0, 0};
  float s2[4] = {0, 0, 0, 0};
  for (int r = blockIdx.x; r < NN; r += gridDim.x) {
    const float* xr = X + (size_t)r * F;
    #pragma unroll
    for (int i = 0; i < 4; ++i) {
      if (i < nf) { float v = xr[tid + i * 256]; s[i] += v; s2[i] += v * v; }
    }
  }
  #pragma unroll
  for (int i = 0; i < 4; ++i) {
    if (i < nf) {
      atomicAdd(&sums[tid + i * 256], s[i]);
      atomicAdd(&sums[F + tid + i * 256], s2[i]);
    }
  }
}

// BN apply -> split bf16 (GEMM A operand)
__global__ void k_bn_apply_split(const float* __restrict__ X, int F,
                                 const float* __restrict__ sums,
                                 const float* __restrict__ gamma,
                                 const float* __restrict__ beta,
                                 unsigned short* __restrict__ Yhi,
                                 unsigned short* __restrict__ Ylo) {
  size_t idx = (size_t)blockIdx.x * blockDim.x + threadIdx.x;
  if (idx >= (size_t)NN * F) return;
  int f = (int)(idx % F);
  const float inv_n = 1.f / NN;
  float mean = sums[f] * inv_n;
  float var  = sums[F + f] * inv_n - mean * mean;
  float sc   = gamma[f] * rsqrtf(var + EPS_BN);
  float v = (X[idx] - mean) * sc + beta[f];
  unsigned short hi, lo;
  split_bf(v, hi, lo);
  Yhi[idx] = hi;
  Ylo[idx] = lo;
}

// BN apply -> single bf16 (gather operand)
__global__ void k_bn_apply_bf16(const float* __restrict__ X, int F,
                                const float* __restrict__ sums,
                                const float* __restrict__ gamma,
                                const float* __restrict__ beta,
                                unsigned short* __restrict__ Y) {
  size_t idx = (size_t)blockIdx.x * blockDim.x + threadIdx.x;
  if (idx >= (size_t)NN * F) return;
  int f = (int)(idx % F);
  const float inv_n = 1.f / NN;
  float mean = sums[f] * inv_n;
  float var  = sums[F + f] * inv_n - mean * mean;
  float sc   = gamma[f] * rsqrtf(var + EPS_BN);
  float v = (X[idx] - mean) * sc + beta[f];
  Y[idx] = f2bf(v);
}

// ------------------------------------------------------------------
// L5 BN fold: sc/sh vectors, scWg, gate const
// ------------------------------------------------------------------
__global__ __launch_bounds__(1024) void k_prep(const float* __restrict__ sums,
                                               const float* __restrict__ g5,
                                               const float* __restrict__ be5,
                                               const float* __restrict__ Wg,
                                               const float* __restrict__ bg,
                                               float* __restrict__ sc, float* __restrict__ sh,
                                               float* __restrict__ scWg, float* __restrict__ gconst) {
  __shared__ float red[1024];
  int f = threadIdx.x;
  const float inv_n = 1.f / NN;
  float mean = sums[f] * inv_n;
  float var  = sums[1024 + f] * inv_n - mean * mean;
  float s = g5[f] * rsqrtf(var + EPS_BN);
  float h = be5[f] - mean * s;
  sc[f] = s; sh[f] = h;
  float wgf = Wg[f];
  scWg[f] = s * wgf;
  red[f] = h * wgf;
  __syncthreads();
  for (int o = 512; o > 0; o >>= 1) {
    if (f < o) red[f] += red[f + o];
    __syncthreads();
  }
  if (f == 0) gconst[0] = red[0] + bg[0];
}

// gate on raw (pre-BN) X with folded affine
__global__ __launch_bounds__(256) void k_gate_aff(const float* __restrict__ X,
                                                  const float* __restrict__ scWg,
                                                  const float* __restrict__ gconst,
                                                  float* __restrict__ gate) {
  __shared__ float red[256];
  int n = blockIdx.x, tid = threadIdx.x;
  const float* xr = X + (size_t)n * 1024;
  float s = 0.f;
  #pragma unroll
  for (int i = 0; i < 4; ++i) { int f = tid + i * 256; s += xr[f] * scWg[f]; }
  red[tid] = s;
  __syncthreads();
  for (int o = 128; o > 0; o >>= 1) {
    if (tid < o) red[tid] += red[tid + o];
    __syncthreads();
  }
  if (tid == 0) gate[n] = red[0] + gconst[0];
}

__global__ __launch_bounds__(64) void k_segred(const float* __restrict__ gate,
                                               const int* __restrict__ goff,
                                               float* __restrict__ gmax,
                                               float* __restrict__ gsum) {
  int g = blockIdx.x, tid = threadIdx.x;
  int beg = goff[g], end = goff[g + 1];
  float m = -3.4e38f;
  for (int n = beg + tid; n < end; n += 64) m = fmaxf(m, gate[n]);
  for (int o = 32; o > 0; o >>= 1) m = fmaxf(m, __shfl_down(m, o, 64));
  m = __shfl(m, 0, 64);
  float s = 0.f;
  for (int n = beg + tid; n < end; n += 64) s += expf(gate[n] - m);
  for (int o = 32; o > 0; o >>= 1) s += __shfl_down(s, o, 64);
  if (tid == 0) { gmax[g] = m; gsum[g] = s; }
}

// pool on raw X, apply affine at the end (sum alpha = 1)
__global__ __launch_bounds__(256) void k_pool_aff(const float* __restrict__ X,
                                                  const float* __restrict__ gate,
                                                  const int* __restrict__ goff,
                                                  const float* __restrict__ gmax,
                                                  const float* __restrict__ gsum,
                                                  const float* __restrict__ sc,
                                                  const float* __restrict__ sh,
                                                  float* __restrict__ pooled) {
  int g = blockIdx.x, tid = threadIdx.x;
  int beg = goff[g], end = goff[g + 1];
  float acc[4] = {0.f, 0.f, 0.f, 0.f};
  bool nonempty = end > beg;
  if (nonempty) {
    float m = gmax[g], inv = 1.f / gsum[g];
    for (int n = beg; n < end; ++n) {
      float a = expf(gate[n] - m) * inv;
      const float* xr = X + (size_t)n * 1024;
      #pragma unroll
      for (int i = 0; i < 4; ++i) acc[i] += a * xr[tid + i * 256];
    }
  }
  #pragma unroll
  for (int i = 0; i < 4; ++i) {
    int f = tid + i * 256;
    float v = nonempty ? (acc[i] * sc[f] + sh[f]) : 0.f;
    pooled[(size_t)g * 1024 + f] = v;
  }
}

// ------------------------------------------------------------------
// MLP head
// ------------------------------------------------------------------
__global__ __launch_bounds__(128) void k_head(const float* __restrict__ pooled,
                                              const float* __restrict__ Wf2, const float* __restrict__ bf2,
                                              const float* __restrict__ Wf3, const float* __restrict__ bf3,
                                              const float* __restrict__ Wf4, const float* __restrict__ bf4,
                                              float* __restrict__ out) {
  __shared__ float sp[1024];
  __shared__ float sp2[128];
  __shared__ float sp3[16];
  int g = blockIdx.x, tid = threadIdx.x;
  #pragma unroll
  for (int i = 0; i < 8; ++i) sp[tid + i * 128] = pooled[(size_t)g * 1024 + tid + i * 128];
  __syncthreads();
  float s = bf2[tid];
  for (int k = 0; k < 1024; ++k) s += sp[k] * Wf2[k * 128 + tid];
  sp2[tid] = fmaxf(s, 0.f);
  __syncthreads();
  if (tid < 16) {
    float t = bf3[tid];
    for (int k = 0; k < 128; ++k) t += sp2[k] * Wf3[k * 16 + tid];
    sp3[tid] = fmaxf(t, 0.f);
  }
  __syncthreads();
  if (tid == 0) {
    float t = bf4[0];
    for (int k = 0; k < 16; ++k) t += sp3[k] * Wf4[k];
    out[g] = t;
  }
}

// ------------------------------------------------------------------
extern "C" void kernel_launch(void* const* d_in, const int* in_sizes, int n_in,
                              void* d_out, int out_size, void* d_ws, size_t ws_size,
                              hipStream_t stream) {
  const float* x     = (const float*)d_in[0];
  const int*   ei    = (const int*)d_in[1];
  const int*   batch = (const int*)d_in[2];
  const float* W[5]; const float* b[5]; const float* g[5]; const float* be[5];
  for (int l = 0; l < 5; ++l) {
    W[l]  = (const float*)d_in[3 + 4 * l];
    b[l]  = (const float*)d_in[4 + 4 * l];
    g[l]  = (const float*)d_in[5 + 4 * l];
    be[l] = (const float*)d_in[6 + 4 * l];
  }
  const float* Wg  = (const float*)d_in[23];
  const float* bg  = (const float*)d_in[24];
  const float* Wf2 = (const float*)d_in[25];
  const float* bf2 = (const float*)d_in[26];
  const float* Wf3 = (const float*)d_in[27];
  const float* bf3 = (const float*)d_in[28];
  const float* Wf4 = (const float*)d_in[29];
  const float* bf4 = (const float*)d_in[30];
  float* out = (float*)d_out;

  const int* row = ei;
  const int* col = ei + NE;

  char* base = (char*)d_ws;
  size_t off = 0;
  auto alloc = [&](size_t bytes) -> char* {
    char* p = base + off;
    off = (off + bytes + 255) & ~(size_t)255;
    return p;
  };
  float* B0  = (float*)alloc((size_t)NN * 1024 * 4);
  unsigned short* Ahi = (unsigned short*)alloc((size_t)MPAD * 1024 * 2);
  unsigned short* Alo = (unsigned short*)alloc((size_t)MPAD * 1024 * 2);
  unsigned short* BF  = (unsigned short*)alloc((size_t)NN * 512 * 2);  // bf16 gather operand
  const int wtsz[5] = {1024 * 32, 512 * 1024, 256 * 512, 512 * 256, 1024 * 512};
  unsigned short* WTh[5]; unsigned short* WTl[5];
  for (int l = 0; l < 5; ++l) {
    WTh[l] = (unsigned short*)alloc((size_t)wtsz[l] * 2);
    WTl[l] = (unsigned short*)alloc((size_t)wtsz[l] * 2);
  }
  float* dinv    = (float*)alloc(NN * 4);
  int*   deg     = (int*)alloc(NN * 4);
  int*   indptr  = (int*)alloc((NN + 1) * 4);
  int*   cursor  = (int*)alloc(NN * 4);
  int*   csr_src = (int*)alloc((size_t)NTOT * 4);
  float* csr_w   = (float*)alloc((size_t)NTOT * 4);
  int*   gcnt    = (int*)alloc(NG * 4);
  int*   goff    = (int*)alloc((NG + 1) * 4);
  int*   gcur    = (int*)alloc(NG * 4);
  float* gate    = (float*)alloc(NN * 4);
  float* gmax    = (float*)alloc(NG * 4);
  float* gsum    = (float*)alloc(NG * 4);
  float* pooled  = (float*)alloc((size_t)NG * 1024 * 4);
  float* bnsum   = (float*)alloc(2 * 1024 * 4);
  float* scv     = (float*)alloc(1024 * 4);
  float* shv     = (float*)alloc(1024 * 4);
  float* scWg    = (float*)alloc(1024 * 4);
  float* gconst  = (float*)alloc(4);

  // ---- preprocessing ----
  hipMemsetAsync(deg, 0, NN * 4, stream);
  hipMemsetAsync(gcnt, 0, NG * 4, stream);
  k_deg<<<(NTOT + 255) / 256, 256, 0, stream>>>(col, deg);
  k_dinv<<<(NN + 255) / 256, 256, 0, stream>>>(deg, dinv);
  k_scan<<<1, 1024, 0, stream>>>(deg, NN, indptr, cursor);
  k_fill<<<(NTOT + 255) / 256, 256, 0, stream>>>(row, col, dinv, cursor, csr_src, csr_w);
  k_gcnt<<<(NN + 255) / 256, 256, 0, stream>>>(batch, gcnt);
  k_scan<<<1, 1024, 0, stream>>>(gcnt, NG, goff, gcur);

  // ---- weight split/transpose ----
  const int wK[5]  = {29, 1024, 512, 256, 512};
  const int wN[5]  = {1024, 512, 256, 512, 1024};
  const int wKp[5] = {32, 1024, 512, 256, 512};
  for (int l = 0; l < 5; ++l) {
    int tot = wN[l] * wKp[l];
    k_wconv<<<(tot + 255) / 256, 256, 0, stream>>>(W[l], wK[l], wN[l], wKp[l], WTh[l], WTl[l]);
  }

  auto gemm_f32 = [&](int l, const float* bias, float* C, int N, int K, int relu) {
    dim3 grid(N / 128, MPAD / 128);
    k_gemm_mfma<<<grid, 256, 0, stream>>>(Ahi, Alo, WTh[l], WTl[l], bias, C, nullptr, NN, N, K, relu);
  };
  auto gemm_bf = [&](int l, int N, int K) {
    dim3 grid(N / 128, MPAD / 128);
    k_gemm_mfma<<<grid, 256, 0, stream>>>(Ahi, Alo, WTh[l], WTl[l], nullptr, nullptr, BF, NN, N, K, 0);
  };
  auto bnstats = [&](const float* H, int F) {
    hipMemsetAsync(bnsum, 0, 2 * F * sizeof(float), stream);
    k_bn_stats<<<512, 256, 0, stream>>>(H, F, bnsum);
  };

  // ---- layer 1 (29 -> 1024): aggregate first on 29 feats (into Ahi/Alo, stride 32) ----
  k_agg_split<<<NN, AGG_T, 0, stream>>>(x, 29, 32, indptr, csr_src, csr_w, Ahi, Alo);
  gemm_f32(0, b[0], B0, 1024, 32, 1);
  bnstats(B0, 1024);
  k_bn_apply_split<<<(int)(((size_t)NN * 1024 + 255) / 256), 256, 0, stream>>>(
      B0, 1024, bnsum, g[0], be[0], Ahi, Alo);

  // ---- layer 2 (1024 -> 512): transform (bf16 out), aggregate on 512 ----
  gemm_bf(1, 512, 1024);
  k_agg_bf<8, false><<<NN / 4, 256, 0, stream>>>(BF, indptr, csr_src, csr_w, b[1], B0, nullptr, nullptr);
  bnstats(B0, 512);
  k_bn_apply_split<<<(int)(((size_t)NN * 512 + 255) / 256), 256, 0, stream>>>(
      B0, 512, bnsum, g[1], be[1], Ahi, Alo);

  // ---- layer 3 (512 -> 256): transform (bf16 out), aggregate on 256 ----
  gemm_bf(2, 256, 512);
  k_agg_bf<4, false><<<NN / 4, 256, 0, stream>>>(BF, indptr, csr_src, csr_w, b[2], B0, nullptr, nullptr);
  bnstats(B0, 256);
  k_bn_apply_bf16<<<(int)(((size_t)NN * 256 + 255) / 256), 256, 0, stream>>>(
      B0, 256, bnsum, g[2], be[2], BF);

  // ---- layer 4 (256 -> 512): aggregate bf16 (split out), transform ----
  k_agg_bf<4, true><<<NN / 4, 256, 0, stream>>>(BF, indptr, csr_src, csr_w, nullptr, nullptr, Ahi, Alo);
  gemm_f32(3, b[3], B0, 512, 256, 1);
  bnstats(B0, 512);
  k_bn_apply_bf16<<<(int)(((size_t)NN * 512 + 255) / 256), 256, 0, stream>>>(
      B0, 512, bnsum, g[3], be[3], BF);

  // ---- layer 5 (512 -> 1024): aggregate bf16 (split out), transform ----
  k_agg_bf<8, true><<<NN / 4, 256, 0, stream>>>(BF, indptr, csr_src, csr_w, nullptr, nullptr, Ahi, Alo);
  gemm_f32(4, b[4], B0, 1024, 512, 1);
  bnstats(B0, 1024);

  // ---- attention pooling with folded BN affine ----
  k_prep<<<1, 1024, 0, stream>>>(bnsum, g[4], be[4], Wg, bg, scv, shv, scWg, gconst);
  k_gate_aff<<<NN, 256, 0, stream>>>(B0, scWg, gconst, gate);
  k_segred<<<NG, 64, 0, stream>>>(gate, goff, gmax, gsum);
  k_pool_aff<<<NG, 256, 0, stream>>>(B0, gate, goff, gmax, gsum, scv, shv, pooled);

  // ---- MLP head ----
  k_head<<<NG, 128, 0, stream>>>(pooled, Wf2, bf2, Wf3, bf3, Wf4, bf4, out);
}

// Round 4
// 713.600 us; speedup vs baseline: 6.1116x; 1.5358x over previous
//
#include <hip/hip_runtime.h>

#define EPS_BN 1e-5f

constexpr int NN   = 20000;       // nodes
constexpr int NE   = 320000;      // edges
constexpr int NTOT = NE + NN;     // edges + self loops
constexpr int NG   = 512;         // graphs
constexpr int MPAD = 20480;       // 160 * 128 rows (pad for clean XCD swizzle)

typedef _Float16 half8  __attribute__((ext_vector_type(8)));
typedef _Float16 half2v __attribute__((ext_vector_type(2)));
typedef float floatx4   __attribute__((ext_vector_type(4)));

__device__ __forceinline__ void gload_lds16(const void* g, void* l) {
  __builtin_amdgcn_global_load_lds(
      (const __attribute__((address_space(1))) void*)g,
      (__attribute__((address_space(3))) void*)l, 16, 0, 0);
}

// ------------------------------------------------------------------
// Graph preprocessing
// ------------------------------------------------------------------
__global__ void k_deg(const int* __restrict__ col, int* __restrict__ deg) {
  int e = blockIdx.x * blockDim.x + threadIdx.x;
  if (e >= NTOT) return;
  int c = (e < NE) ? col[e] : (e - NE);
  atomicAdd(&deg[c], 1);
}

__global__ void k_dinv(const int* __restrict__ deg, float* __restrict__ dinv) {
  int i = blockIdx.x * blockDim.x + threadIdx.x;
  if (i < NN) dinv[i] = rsqrtf((float)deg[i]);
}

__global__ __launch_bounds__(1024) void k_scan(const int* __restrict__ counts, int n,
                                               int* __restrict__ out_ptr,
                                               int* __restrict__ cursor) {
  __shared__ int ssum[1024];
  int tid = threadIdx.x;
  int per = (n + 1023) / 1024;
  int beg = tid * per;
  int end = min(beg + per, n);
  int s = 0;
  for (int i = beg; i < end; ++i) s += counts[i];
  ssum[tid] = s;
  __syncthreads();
  for (int off = 1; off < 1024; off <<= 1) {
    int v = ssum[tid];
    int add = (tid >= off) ? ssum[tid - off] : 0;
    __syncthreads();
    ssum[tid] = v + add;
    __syncthreads();
  }
  int excl = (tid == 0) ? 0 : ssum[tid - 1];
  for (int i = beg; i < end; ++i) {
    out_ptr[i] = excl;
    cursor[i]  = excl;
    excl += counts[i];
  }
  if (tid == 1023) out_ptr[n] = ssum[1023];
}

__global__ void k_fill(const int* __restrict__ row, const int* __restrict__ col,
                       const float* __restrict__ dinv, int* __restrict__ cursor,
                       int* __restrict__ csr_src, float* __restrict__ csr_w) {
  int e = blockIdx.x * blockDim.x + threadIdx.x;
  if (e >= NTOT) return;
  int r, c;
  if (e < NE) { r = row[e]; c = col[e]; } else { r = c = e - NE; }
  int pos = atomicAdd(&cursor[c], 1);
  csr_src[pos] = r;
  csr_w[pos]   = dinv[r] * dinv[c];
}

__global__ void k_rowsum(const int* __restrict__ indptr, const float* __restrict__ w,
                         float* __restrict__ s) {
  int n = blockIdx.x * blockDim.x + threadIdx.x;
  if (n >= NN) return;
  float t = 0.f;
  int e0 = indptr[n], e1 = indptr[n + 1];
  for (int e = e0; e < e1; ++e) t += w[e];
  s[n] = t;
}

__global__ void k_gcnt(const int* __restrict__ batch, int* __restrict__ cnt) {
  int n = blockIdx.x * blockDim.x + threadIdx.x;
  if (n < NN) atomicAdd(&cnt[batch[n]], 1);
}

// ------------------------------------------------------------------
// Weight conversion / BN-fold
// ------------------------------------------------------------------
__global__ void k_wconv16(const float* __restrict__ W, int K, int N, int Kp,
                          _Float16* __restrict__ T) {
  int idx = blockIdx.x * blockDim.x + threadIdx.x;
  if (idx >= N * Kp) return;
  int n = idx / Kp, k = idx - n * Kp;
  float v = (k < K) ? W[(size_t)k * N + n] : 0.f;
  T[idx] = (_Float16)v;
}

// W' = diag(sc) W transposed to [N,K] fp16; c[n] = sum_k sh_k W[k,n]
__global__ __launch_bounds__(256) void k_wfold(const float* __restrict__ W, int K, int N,
                                               const float* __restrict__ sums,
                                               const float* __restrict__ gamma,
                                               const float* __restrict__ beta,
                                               _Float16* __restrict__ T,
                                               float* __restrict__ c) {
  __shared__ float red[256];
  int n = blockIdx.x, tid = threadIdx.x;
  const float inv_n = 1.f / NN;
  float csum = 0.f;
  for (int k = tid; k < K; k += 256) {
    float mean = sums[k] * inv_n;
    float var  = sums[K + k] * inv_n - mean * mean;
    float sc   = gamma[k] * rsqrtf(var + EPS_BN);
    float sh   = beta[k] - mean * sc;
    float wv   = W[(size_t)k * N + n];
    T[(size_t)n * K + k] = (_Float16)(sc * wv);
    csum += sh * wv;
  }
  red[tid] = csum;
  __syncthreads();
  for (int o = 128; o > 0; o >>= 1) {
    if (tid < o) red[tid] += red[tid + o];
    __syncthreads();
  }
  if (tid == 0) c[n] = red[0];
}

__global__ void k_bnvec(const float* __restrict__ sums, int F,
                        const float* __restrict__ gamma, const float* __restrict__ beta,
                        float* __restrict__ sc, float* __restrict__ sh) {
  int f = blockIdx.x * blockDim.x + threadIdx.x;
  if (f >= F) return;
  const float inv_n = 1.f / NN;
  float mean = sums[f] * inv_n;
  float var  = sums[F + f] * inv_n - mean * mean;
  float s = gamma[f] * rsqrtf(var + EPS_BN);
  sc[f] = s;
  sh[f] = beta[f] - mean * s;
}

// ------------------------------------------------------------------
// L1 aggregation: fp32 x (F=29) -> fp16 out (stride 32)
// ------------------------------------------------------------------
#define AGG_T  128
#define AGG_CH 128
__global__ __launch_bounds__(AGG_T) void k_agg29(
    const float* __restrict__ X,
    const int* __restrict__ indptr, const int* __restrict__ src,
    const float* __restrict__ w,
    _Float16* __restrict__ Y) {
  __shared__ int   s_src[AGG_CH];
  __shared__ float s_w[AGG_CH];
  int node = blockIdx.x;
  int tid  = threadIdx.x;
  int beg = indptr[node], end = indptr[node + 1];
  float acc = 0.f;
  for (int e0 = beg; e0 < end; e0 += AGG_CH) {
    int c = min(AGG_CH, end - e0);
    if (tid < c) { s_src[tid] = src[e0 + tid]; s_w[tid] = w[e0 + tid]; }
    __syncthreads();
    for (int j = 0; j < c; ++j) {
      if (tid < 29) acc += s_w[j] * X[(size_t)s_src[j] * 29 + tid];
    }
    __syncthreads();
  }
  if (tid < 32) Y[(size_t)node * 32 + tid] = (tid < 29) ? (_Float16)acc : (_Float16)0.f;
}

// ------------------------------------------------------------------
// fp16 gather aggregation, wave-per-node (4 nodes/block). F = 64*VEC.
// MODE 0: out = relu(acc + s*c[f] + bias[f])     (post-transform agg)
// MODE 1: out = sc[f]*acc + s*sh[f]              (BN folded into agg)
// ------------------------------------------------------------------
template<int VEC, int MODE>
__global__ __launch_bounds__(256) void k_aggf(
    const _Float16* __restrict__ X, _Float16* __restrict__ Y,
    const int* __restrict__ indptr, const int* __restrict__ src,
    const float* __restrict__ w, const float* __restrict__ rowsum,
    const float* __restrict__ v1, const float* __restrict__ v2)
{
  constexpr int F = 64 * VEC;
  int wave = threadIdx.x >> 6;
  int lane = threadIdx.x & 63;
  int node = blockIdx.x * 4 + wave;
  if (node >= NN) return;
  int beg = indptr[node], end = indptr[node + 1];
  float acc[VEC];
  #pragma unroll
  for (int i = 0; i < VEC; ++i) acc[i] = 0.f;
  const unsigned int* Xl = (const unsigned int*)X + lane * (VEC / 2);

  auto body = [&](int e) {
    int s = src[e];
    float we = w[e];
    const unsigned int* xr = Xl + (size_t)s * (F / 2);
    unsigned int u[VEC / 2];
    if constexpr (VEC == 8) {
      uint4 d = *(const uint4*)xr;
      u[0] = d.x; u[1] = d.y; u[2] = d.z; u[3] = d.w;
    } else {
      uint2 d = *(const uint2*)xr;
      u[0] = d.x; u[1] = d.y;
    }
    #pragma unroll
    for (int i = 0; i < VEC / 2; ++i) {
      half2v h = __builtin_bit_cast(half2v, u[i]);
      acc[2 * i]     = fmaf(we, (float)h[0], acc[2 * i]);
      acc[2 * i + 1] = fmaf(we, (float)h[1], acc[2 * i + 1]);
    }
  };
  int e = beg;
  for (; e + 2 <= end; e += 2) { body(e); body(e + 1); }
  if (e < end) body(e);

  float s_n = rowsum[node];
  size_t obase = (size_t)node * F + lane * VEC;
  #pragma unroll
  for (int i = 0; i < VEC; ++i) {
    int f = lane * VEC + i;
    float v;
    if constexpr (MODE == 0) v = fmaxf(acc[i] + s_n * v1[f] + v2[f], 0.f);
    else                     v = v1[f] * acc[i] + s_n * v2[f];
    Y[obase + i] = (_Float16)v;
  }
}

// ------------------------------------------------------------------
// fp16 MFMA GEMM, 128x128 tile, XCD-swizzled 1-D grid (nbx * 160 blocks).
// A: [MPAD,K] fp16 row-major. B^T: [N,K] fp16. Out: fp32 Cf or fp16 Ch.
// Optional fused bias/relu and BN stats (sum/sumsq per output feature).
// ------------------------------------------------------------------
__global__ __launch_bounds__(256) void k_gemm16(
    const _Float16* __restrict__ A, const _Float16* __restrict__ B,
    const float* __restrict__ bias,
    float* __restrict__ Cf, _Float16* __restrict__ Ch,
    float* __restrict__ stats,
    int N, int K, int do_relu, int nbx)
{
  __shared__ __align__(16) _Float16 sA[128 * 32];
  __shared__ __align__(16) _Float16 sB[128 * 32];
  __shared__ float sred[256];

  const int tid  = threadIdx.x;
  const int wave = tid >> 6;
  const int lane = tid & 63;

  // XCD swizzle: all column strips of one row-panel land on one XCD
  int lin = blockIdx.x;
  int xcd = lin & 7, seq = lin >> 3;
  int bx = seq % nbx, grp = seq / nbx;
  int by = xcd + 8 * grp;            // 0..159
  const int row0 = by * 128;
  const int col0 = bx * 128;

  const int q  = lane >> 4;
  const int mm = lane & 15;
  const int wm = wave >> 1;
  const int wn = wave & 1;
  const int srow = lane >> 2;
  const int skel = (lane & 3) * 8;

  sred[tid] = 0.f;

  floatx4 acc[4][4];
  #pragma unroll
  for (int i = 0; i < 4; ++i)
    #pragma unroll
    for (int j = 0; j < 4; ++j) acc[i][j] = floatx4{0.f, 0.f, 0.f, 0.f};

  for (int k0 = 0; k0 < K; k0 += 32) {
    #pragma unroll
    for (int r = 0; r < 2; ++r) {
      int trow = wave * 32 + r * 16;
      gload_lds16(A + (size_t)(row0 + trow + srow) * K + k0 + skel, &sA[trow * 32]);
      gload_lds16(B + (size_t)(col0 + trow + srow) * K + k0 + skel, &sB[trow * 32]);
    }
    __syncthreads();

    half8 av[4];
    #pragma unroll
    for (int i = 0; i < 4; ++i)
      av[i] = *(const half8*)&sA[(wm * 64 + i * 16 + mm) * 32 + q * 8];
    #pragma unroll
    for (int j = 0; j < 4; ++j) {
      half8 bv = *(const half8*)&sB[(wn * 64 + j * 16 + mm) * 32 + q * 8];
      #pragma unroll
      for (int i = 0; i < 4; ++i)
        acc[i][j] = __builtin_amdgcn_mfma_f32_16x16x32_f16(av[i], bv, acc[i][j], 0, 0, 0);
    }
    __syncthreads();
  }

  float sloc[4] = {0.f, 0.f, 0.f, 0.f};
  float s2loc[4] = {0.f, 0.f, 0.f, 0.f};
  #pragma unroll
  for (int j = 0; j < 4; ++j) {
    int cc = col0 + wn * 64 + j * 16 + mm;
    float bv = bias ? bias[cc] : 0.f;
    #pragma unroll
    for (int i = 0; i < 4; ++i) {
      #pragma unroll
      for (int r = 0; r < 4; ++r) {
        int rr = row0 + wm * 64 + i * 16 + q * 4 + r;
        if (rr < NN) {
          float v = acc[i][j][r] + bv;
          if (do_relu) v = fmaxf(v, 0.f);
          if (Cf) Cf[(size_t)rr * N + cc] = v;
          else    Ch[(size_t)rr * N + cc] = (_Float16)v;
          sloc[j]  += v;
          s2loc[j] += v * v;
        }
      }
    }
  }

  if (stats) {
    #pragma unroll
    for (int j = 0; j < 4; ++j) {
      float a = sloc[j], b2 = s2loc[j];
      a  += __shfl_xor(a, 16, 64);  a  += __shfl_xor(a, 32, 64);
      b2 += __shfl_xor(b2, 16, 64); b2 += __shfl_xor(b2, 32, 64);
      if (q == 0) {
        int cl = wn * 64 + j * 16 + mm;   // 0..127
        atomicAdd(&sred[cl], a);
        atomicAdd(&sred[128 + cl], b2);
      }
    }
    __syncthreads();
    if (tid < 128) {
      atomicAdd(&stats[col0 + tid], sred[tid]);
      atomicAdd(&stats[N + col0 + tid], sred[128 + tid]);
    }
  }
}

// ------------------------------------------------------------------
// Slim BN stats over fp16 tensor (stride == F)
// ------------------------------------------------------------------
__global__ __launch_bounds__(256) void k_stats16(const _Float16* __restrict__ X, int F,
                                                 float* __restrict__ sums) {
  int tid = threadIdx.x;
  int npf = F >> 8;   // 1 or 2
  float s[2] = {0.f, 0.f}, s2[2] = {0.f, 0.f};
  for (int r = blockIdx.x; r < NN; r += gridDim.x) {
    #pragma unroll
    for (int i = 0; i < 2; ++i) {
      if (i < npf) {
        float v = (float)X[(size_t)r * F + tid + i * 256];
        s[i] += v; s2[i] += v * v;
      }
    }
  }
  #pragma unroll
  for (int i = 0; i < 2; ++i) {
    if (i < npf) {
      atomicAdd(&sums[tid + i * 256], s[i]);
      atomicAdd(&sums[F + tid + i * 256], s2[i]);
    }
  }
}

// ------------------------------------------------------------------
// L5 BN fold for pooling: sc/sh vectors, scWg, gate const
// ------------------------------------------------------------------
__global__ __launch_bounds__(1024) void k_prep(const float* __restrict__ sums,
                                               const float* __restrict__ g5,
                                               const float* __restrict__ be5,
                                               const float* __restrict__ Wg,
                                               const float* __restrict__ bg,
                                               float* __restrict__ sc, float* __restrict__ sh,
                                               float* __restrict__ scWg, float* __restrict__ gconst) {
  __shared__ float red[1024];
  int f = threadIdx.x;
  const float inv_n = 1.f / NN;
  float mean = sums[f] * inv_n;
  float var  = sums[1024 + f] * inv_n - mean * mean;
  float s = g5[f] * rsqrtf(var + EPS_BN);
  float h = be5[f] - mean * s;
  sc[f] = s; sh[f] = h;
  float wgf = Wg[f];
  scWg[f] = s * wgf;
  red[f] = h * wgf;
  __syncthreads();
  for (int o = 512; o > 0; o >>= 1) {
    if (f < o) red[f] += red[f + o];
    __syncthreads();
  }
  if (f == 0) gconst[0] = red[0] + bg[0];
}

__global__ __launch_bounds__(256) void k_gate_aff(const float* __restrict__ X,
                                                  const float* __restrict__ scWg,
                                                  const float* __restrict__ gconst,
                                                  float* __restrict__ gate) {
  __shared__ float red[256];
  int n = blockIdx.x, tid = threadIdx.x;
  const float* xr = X + (size_t)n * 1024;
  float s = 0.f;
  #pragma unroll
  for (int i = 0; i < 4; ++i) { int f = tid + i * 256; s += xr[f] * scWg[f]; }
  red[tid] = s;
  __syncthreads();
  for (int o = 128; o > 0; o >>= 1) {
    if (tid < o) red[tid] += red[tid + o];
    __syncthreads();
  }
  if (tid == 0) gate[n] = red[0] + gconst[0];
}

__global__ __launch_bounds__(64) void k_segred(const float* __restrict__ gate,
                                               const int* __restrict__ goff,
                                               float* __restrict__ gmax,
                                               float* __restrict__ gsum) {
  int g = blockIdx.x, tid = threadIdx.x;
  int beg = goff[g], end = goff[g + 1];
  float m = -3.4e38f;
  for (int n = beg + tid; n < end; n += 64) m = fmaxf(m, gate[n]);
  for (int o = 32; o > 0; o >>= 1) m = fmaxf(m, __shfl_down(m, o, 64));
  m = __shfl(m, 0, 64);
  float s = 0.f;
  for (int n = beg + tid; n < end; n += 64) s += expf(gate[n] - m);
  for (int o = 32; o > 0; o >>= 1) s += __shfl_down(s, o, 64);
  if (tid == 0) { gmax[g] = m; gsum[g] = s; }
}

__global__ __launch_bounds__(256) void k_pool_aff(const float* __restrict__ X,
                                                  const float* __restrict__ gate,
                                                  const int* __restrict__ goff,
                                                  const float* __restrict__ gmax,
                                                  const float* __restrict__ gsum,
                                                  const float* __restrict__ sc,
                                                  const float* __restrict__ sh,
                                                  float* __restrict__ pooled) {
  int g = blockIdx.x, tid = threadIdx.x;
  int beg = goff[g], end = goff[g + 1];
  float acc[4] = {0.f, 0.f, 0.f, 0.f};
  bool nonempty = end > beg;
  if (nonempty) {
    float m = gmax[g], inv = 1.f / gsum[g];
    for (int n = beg; n < end; ++n) {
      float a = expf(gate[n] - m) * inv;
      const float* xr = X + (size_t)n * 1024;
      #pragma unroll
      for (int i = 0; i < 4; ++i) acc[i] += a * xr[tid + i * 256];
    }
  }
  #pragma unroll
  for (int i = 0; i < 4; ++i) {
    int f = tid + i * 256;
    float v = nonempty ? (acc[i] * sc[f] + sh[f]) : 0.f;
    pooled[(size_t)g * 1024 + f] = v;
  }
}

// ------------------------------------------------------------------
// MLP head
// ------------------------------------------------------------------
__global__ __launch_bounds__(128) void k_head(const float* __restrict__ pooled,
                                              const float* __restrict__ Wf2, const float* __restrict__ bf2,
                                              const float* __restrict__ Wf3, const float* __restrict__ bf3,
                                              const float* __restrict__ Wf4, const float* __restrict__ bf4,
                                              float* __restrict__ out) {
  __shared__ float sp[1024];
  __shared__ float sp2[128];
  __shared__ float sp3[16];
  int g = blockIdx.x, tid = threadIdx.x;
  #pragma unroll
  for (int i = 0; i < 8; ++i) sp[tid + i * 128] = pooled[(size_t)g * 1024 + tid + i * 128];
  __syncthreads();
  float s = bf2[tid];
  for (int k = 0; k < 1024; ++k) s += sp[k] * Wf2[k * 128 + tid];
  sp2[tid] = fmaxf(s, 0.f);
  __syncthreads();
  if (tid < 16) {
    float t = bf3[tid];
    for (int k = 0; k < 128; ++k) t += sp2[k] * Wf3[k * 16 + tid];
    sp3[tid] = fmaxf(t, 0.f);
  }
  __syncthreads();
  if (tid == 0) {
    float t = bf4[0];
    for (int k = 0; k < 16; ++k) t += sp3[k] * Wf4[k];
    out[g] = t;
  }
}

// ------------------------------------------------------------------
extern "C" void kernel_launch(void* const* d_in, const int* in_sizes, int n_in,
                              void* d_out, int out_size, void* d_ws, size_t ws_size,
                              hipStream_t stream) {
  const float* x     = (const float*)d_in[0];
  const int*   ei    = (const int*)d_in[1];
  const int*   batch = (const int*)d_in[2];
  const float* W[5]; const float* b[5]; const float* g[5]; const float* be[5];
  for (int l = 0; l < 5; ++l) {
    W[l]  = (const float*)d_in[3 + 4 * l];
    b[l]  = (const float*)d_in[4 + 4 * l];
    g[l]  = (const float*)d_in[5 + 4 * l];
    be[l] = (const float*)d_in[6 + 4 * l];
  }
  const float* Wg  = (const float*)d_in[23];
  const float* bg  = (const float*)d_in[24];
  const float* Wf2 = (const float*)d_in[25];
  const float* bf2 = (const float*)d_in[26];
  const float* Wf3 = (const float*)d_in[27];
  const float* bf3 = (const float*)d_in[28];
  const float* Wf4 = (const float*)d_in[29];
  const float* bf4 = (const float*)d_in[30];
  float* out = (float*)d_out;

  const int* row = ei;
  const int* col = ei + NE;

  char* base = (char*)d_ws;
  size_t off = 0;
  auto alloc = [&](size_t bytes) -> char* {
    char* p = base + off;
    off = (off + bytes + 255) & ~(size_t)255;
    return p;
  };
  float*     B0  = (float*)alloc((size_t)NN * 1024 * 4);      // h5 (fp32)
  _Float16*  AH  = (_Float16*)alloc((size_t)MPAD * 1024 * 2); // GEMM A operand
  _Float16*  ASM = (_Float16*)alloc((size_t)MPAD * 32 * 2);   // L1 A operand
  _Float16*  BF  = (_Float16*)alloc((size_t)NN * 512 * 2);    // gather buffer
  _Float16*  BF2 = (_Float16*)alloc((size_t)NN * 512 * 2);    // gather buffer
  const int wtsz[5] = {1024 * 32, 512 * 1024, 256 * 512, 512 * 256, 1024 * 512};
  _Float16* WT[5];
  for (int l = 0; l < 5; ++l) WT[l] = (_Float16*)alloc((size_t)wtsz[l] * 2);
  float* c2  = (float*)alloc(512 * 4);
  float* c3  = (float*)alloc(256 * 4);
  float* dinv    = (float*)alloc(NN * 4);
  int*   deg     = (int*)alloc(NN * 4);
  int*   indptr  = (int*)alloc((NN + 1) * 4);
  int*   cursor  = (int*)alloc(NN * 4);
  int*   csr_src = (int*)alloc((size_t)NTOT * 4);
  float* csr_w   = (float*)alloc((size_t)NTOT * 4);
  float* rsum    = (float*)alloc(NN * 4);
  int*   gcnt    = (int*)alloc(NG * 4);
  int*   goff    = (int*)alloc((NG + 1) * 4);
  int*   gcur    = (int*)alloc(NG * 4);
  float* gate    = (float*)alloc(NN * 4);
  float* gmax    = (float*)alloc(NG * 4);
  float* gsum    = (float*)alloc(NG * 4);
  float* pooled  = (float*)alloc((size_t)NG * 1024 * 4);
  float* bns     = (float*)alloc(6656 * 4);
  float* bns1 = bns;          // 2048 (F=1024)
  float* bns2 = bns + 2048;   // 1024 (F=512)
  float* bns3 = bns + 3072;   // 512  (F=256)
  float* bns4 = bns + 3584;   // 1024 (F=512)
  float* bns5 = bns + 4608;   // 2048 (F=1024)
  float* scv3 = (float*)alloc(256 * 4);
  float* shv3 = (float*)alloc(256 * 4);
  float* scv4 = (float*)alloc(512 * 4);
  float* shv4 = (float*)alloc(512 * 4);
  float* scv5 = (float*)alloc(1024 * 4);
  float* shv5 = (float*)alloc(1024 * 4);
  float* scWg = (float*)alloc(1024 * 4);
  float* gconst = (float*)alloc(4);

  // ---- preprocessing ----
  hipMemsetAsync(deg, 0, NN * 4, stream);
  hipMemsetAsync(gcnt, 0, NG * 4, stream);
  hipMemsetAsync(bns, 0, 6656 * 4, stream);
  k_deg<<<(NTOT + 255) / 256, 256, 0, stream>>>(col, deg);
  k_dinv<<<(NN + 255) / 256, 256, 0, stream>>>(deg, dinv);
  k_scan<<<1, 1024, 0, stream>>>(deg, NN, indptr, cursor);
  k_fill<<<(NTOT + 255) / 256, 256, 0, stream>>>(row, col, dinv, cursor, csr_src, csr_w);
  k_rowsum<<<(NN + 255) / 256, 256, 0, stream>>>(indptr, csr_w, rsum);
  k_gcnt<<<(NN + 255) / 256, 256, 0, stream>>>(batch, gcnt);
  k_scan<<<1, 1024, 0, stream>>>(gcnt, NG, goff, gcur);

  // plain weight transposes (W1 pad 29->32, W4, W5)
  k_wconv16<<<(1024 * 32 + 255) / 256, 256, 0, stream>>>(W[0], 29, 1024, 32, WT[0]);
  k_wconv16<<<(512 * 256 + 255) / 256, 256, 0, stream>>>(W[3], 256, 512, 256, WT[3]);
  k_wconv16<<<(1024 * 512 + 255) / 256, 256, 0, stream>>>(W[4], 512, 1024, 512, WT[4]);

  auto gemm = [&](const _Float16* A, int wl, const float* bias,
                  float* Cf, _Float16* Ch, float* stats, int N, int K, int relu) {
    int nbx = N / 128;
    k_gemm16<<<nbx * 160, 256, 0, stream>>>(A, WT[wl], bias, Cf, Ch, stats, N, K, relu, nbx);
  };

  // ---- layer 1 (29 -> 1024): agg-first; GEMM1 fuses bias/relu/stats, out fp16 r1 ----
  k_agg29<<<NN, AGG_T, 0, stream>>>(x, indptr, csr_src, csr_w, ASM);
  gemm(ASM, 0, b[0], nullptr, AH, bns1, 1024, 32, 1);

  // ---- layer 2 (1024 -> 512): BN1 folded into W2; transform-first ----
  k_wfold<<<512, 256, 0, stream>>>(W[1], 1024, 512, bns1, g[0], be[0], WT[1], c2);
  gemm(AH, 1, nullptr, nullptr, BF, nullptr, 512, 1024, 0);      // G2 = r1 W2'
  k_aggf<8, 0><<<NN / 4, 256, 0, stream>>>(BF, AH, indptr, csr_src, csr_w, rsum, c2, b[1]); // r2
  k_stats16<<<512, 256, 0, stream>>>(AH, 512, bns2);

  // ---- layer 3 (512 -> 256): BN2 folded into W3; transform-first ----
  k_wfold<<<256, 256, 0, stream>>>(W[2], 512, 256, bns2, g[1], be[1], WT[2], c3);
  gemm(AH, 2, nullptr, nullptr, BF2, nullptr, 256, 512, 0);      // G3 = r2 W3'
  k_aggf<4, 0><<<NN / 4, 256, 0, stream>>>(BF2, BF, indptr, csr_src, csr_w, rsum, c3, b[2]); // r3
  k_stats16<<<512, 256, 0, stream>>>(BF, 256, bns3);

  // ---- layer 4 (256 -> 512): agg-first with BN3 folded into agg epilogue ----
  k_bnvec<<<1, 256, 0, stream>>>(bns3, 256, g[2], be[2], scv3, shv3);
  k_aggf<4, 1><<<NN / 4, 256, 0, stream>>>(BF, AH, indptr, csr_src, csr_w, rsum, scv3, shv3); // a4
  gemm(AH, 3, b[3], nullptr, BF2, bns4, 512, 256, 1);            // r4 (fp16) + stats

  // ---- layer 5 (512 -> 1024): agg-first with BN4 folded; GEMM5 out fp32 ----
  k_bnvec<<<2, 256, 0, stream>>>(bns4, 512, g[3], be[3], scv4, shv4);
  k_aggf<8, 1><<<NN / 4, 256, 0, stream>>>(BF2, AH, indptr, csr_src, csr_w, rsum, scv4, shv4); // a5
  gemm(AH, 4, b[4], B0, nullptr, bns5, 1024, 512, 1);            // r5 (fp32) + stats

  // ---- attention pooling with folded BN5 affine ----
  k_prep<<<1, 1024, 0, stream>>>(bns5, g[4], be[4], Wg, bg, scv5, shv5, scWg, gconst);
  k_gate_aff<<<NN, 256, 0, stream>>>(B0, scWg, gconst, gate);
  k_segred<<<NG, 64, 0, stream>>>(gate, goff, gmax, gsum);
  k_pool_aff<<<NG, 256, 0, stream>>>(B0, gate, goff, gmax, gsum, scv5, shv5, pooled);

  // ---- MLP head ----
  k_head<<<NG, 128, 0, stream>>>(pooled, Wf2, bf2, Wf3, bf3, Wf4, bf4, out);
}